// Round 8
// baseline (459.248 us; speedup 1.0000x reference)
//
#include <hip/hip_runtime.h>
#include <hip/hip_bf16.h>

#define NPTS 4096
#define CIN 64
#define COUT 128
#define BATCH 8
#define KNN 8
#define NCH 16              // candidates per column-half
#define NCT 32              // total candidates per row
#define TOTROWS (BATCH * NPTS)   // 32768

using short8 = __attribute__((ext_vector_type(8))) short;
using f32x4  = __attribute__((ext_vector_type(4))) float;

__device__ __forceinline__ unsigned short f2bf_rne(float f) {
    unsigned int u = __float_as_uint(f);
    unsigned int r = (u + 0x7fffu + ((u >> 16) & 1u)) >> 16;
    return (unsigned short)r;
}

// ---------------- Kernel 1: pack x -> hi/lo bf16 rows (256B) + exact row norms ----------------
__global__ __launch_bounds__(256) void prep_kernel(const float* __restrict__ x,
                                                   unsigned short* __restrict__ xpack,
                                                   float* __restrict__ xxf,
                                                   double* __restrict__ xxd) {
    int i   = blockIdx.x * 256 + threadIdx.x;    // 0 .. 262143
    int row = i >> 3, g = i & 7;                 // 8 threads per row
    const float* src = x + (size_t)row * CIN + g * 8;
    float4 v0 = *(const float4*)src;
    float4 v1 = *(const float4*)(src + 4);
    float f[8] = {v0.x, v0.y, v0.z, v0.w, v1.x, v1.y, v1.z, v1.w};

    unsigned int h[8]; unsigned short l[8];
    double s = 0.0;
    #pragma unroll
    for (int j = 0; j < 8; ++j) {
        unsigned int b  = __float_as_uint(f[j]);
        unsigned int hm = b & 0xFFFF0000u;
        h[j] = hm >> 16;
        l[j] = f2bf_rne(f[j] - __uint_as_float(hm));
        s += (double)f[j] * (double)f[j];
    }
    uint4 hi, lo;
    hi.x = h[0] | (h[1] << 16); hi.y = h[2] | (h[3] << 16);
    hi.z = h[4] | (h[5] << 16); hi.w = h[6] | (h[7] << 16);
    lo.x = (unsigned int)l[0] | ((unsigned int)l[1] << 16);
    lo.y = (unsigned int)l[2] | ((unsigned int)l[3] << 16);
    lo.z = (unsigned int)l[4] | ((unsigned int)l[5] << 16);
    lo.w = (unsigned int)l[6] | ((unsigned int)l[7] << 16);
    unsigned short* dst = xpack + (size_t)row * 128;
    *(uint4*)&dst[g * 8]      = hi;
    *(uint4*)&dst[64 + g * 8] = lo;

    s += __shfl_xor(s, 1);
    s += __shfl_xor(s, 2);
    s += __shfl_xor(s, 4);
    if (g == 0) { xxf[row] = (float)s; xxd[row] = s; }
}

// ---------------- Kernel 2: split-bf16 MFMA scores -> med3-chain top-8/lane -> top-16/half ----------------
// key = float(score + 1000) with low 7 mantissa bits replaced by stream position p = mt*4+ct.
// All keys positive floats => float order == unsigned order; truncation error <=0.016 << gaps;
// rerank is exact fp64 anyway. Insert: new[0]=max(old[0],t); new[j]=med3(t, old[j-1], old[j]).
__global__ __launch_bounds__(256, 4) void knn_cand_kernel(const unsigned short* __restrict__ xpack,
                                                          const float* __restrict__ xxf,
                                                          int* __restrict__ cand) {
    __shared__ __align__(16) unsigned short P[2][64 * 136];
    __shared__ float xxm[2][64];

    const int tid  = threadIdx.x;
    const int n0   = blockIdx.x * 64;
    const int half = blockIdx.y;
    const int b    = blockIdx.z;
    const int wave = tid >> 6;
    const int lane = tid & 63;
    const int lrow = lane & 15;
    const int quad = lane >> 4;
    const int colT0 = half * 32;                 // first 64-col tile of this half

    const unsigned short* xp = xpack + ((size_t)b << 12) * 128;

    // stage A tile (rows n0..n0+63) into P[0]
    for (int G = tid; G < 1024; G += 256) {
        int row = G >> 4, g = G & 15;
        *(uint4*)&P[0][row * 136 + g * 8] = *(const uint4*)&xp[(size_t)(n0 + row) * 128 + g * 8];
    }
    __syncthreads();

    const int arow = (wave * 16 + lrow) * 136;
    short8 ah0 = *(const short8*)&P[0][arow + quad * 8];
    short8 ah1 = *(const short8*)&P[0][arow + 32 + quad * 8];
    short8 al0 = *(const short8*)&P[0][arow + 64 + quad * 8];
    short8 al1 = *(const short8*)&P[0][arow + 96 + quad * 8];

    // stage B tile 0 into P[1]
    {
        uint4 r0[4];
        const int G0 = tid * 4;
        #pragma unroll
        for (int k = 0; k < 4; ++k) {
            int G = G0 + k, row = G >> 4, g = G & 15;
            r0[k] = *(const uint4*)&xp[(size_t)(colT0 * 64 + row) * 128 + g * 8];
        }
        float xv = (tid < 64) ? (1000.f - xxf[(b << 12) + colT0 * 64 + tid]) : 0.f;
        #pragma unroll
        for (int k = 0; k < 4; ++k) {
            int G = G0 + k, row = G >> 4, g = G & 15;
            *(uint4*)&P[1][row * 136 + g * 8] = r0[k];
        }
        if (tid < 64) xxm[0][tid] = xv;
    }
    __syncthreads();

    // per-lane: 4 row-lists (rows wave*16+quad*4+r), each sorted-desc 8 float keys
    float keys[4][8];
    #pragma unroll
    for (int r = 0; r < 4; ++r)
        #pragma unroll
        for (int j = 0; j < 8; ++j) keys[r][j] = 0.f;

    for (int mt = 0; mt < 32; ++mt) {
        unsigned short* cur = P[1 - (mt & 1)];
        unsigned short* nxt = P[mt & 1];

        uint4 pr[4]; float pxv = 0.f;
        const int G0 = tid * 4;
        if (mt + 1 < 32) {
            const int tnext = colT0 + mt + 1;
            #pragma unroll
            for (int k = 0; k < 4; ++k) {
                int G = G0 + k, row = G >> 4, g = G & 15;
                pr[k] = *(const uint4*)&xp[(size_t)(tnext * 64 + row) * 128 + g * 8];
            }
            if (tid < 64) pxv = 1000.f - xxf[(b << 12) + tnext * 64 + tid];
        }

        #pragma unroll
        for (int ct = 0; ct < 4; ++ct) {
            const int brow = (ct * 16 + lrow) * 136;
            short8 bh0 = *(const short8*)&cur[brow + quad * 8];
            short8 bh1 = *(const short8*)&cur[brow + 32 + quad * 8];
            short8 bl0 = *(const short8*)&cur[brow + 64 + quad * 8];
            short8 bl1 = *(const short8*)&cur[brow + 96 + quad * 8];
            f32x4 acc = {0.f, 0.f, 0.f, 0.f};
            acc = __builtin_amdgcn_mfma_f32_16x16x32_bf16(al0, bl0, acc, 0, 0, 0);
            acc = __builtin_amdgcn_mfma_f32_16x16x32_bf16(al1, bl1, acc, 0, 0, 0);
            acc = __builtin_amdgcn_mfma_f32_16x16x32_bf16(ah0, bl0, acc, 0, 0, 0);
            acc = __builtin_amdgcn_mfma_f32_16x16x32_bf16(ah1, bl1, acc, 0, 0, 0);
            acc = __builtin_amdgcn_mfma_f32_16x16x32_bf16(al0, bh0, acc, 0, 0, 0);
            acc = __builtin_amdgcn_mfma_f32_16x16x32_bf16(al1, bh1, acc, 0, 0, 0);
            acc = __builtin_amdgcn_mfma_f32_16x16x32_bf16(ah0, bh0, acc, 0, 0, 0);
            acc = __builtin_amdgcn_mfma_f32_16x16x32_bf16(ah1, bh1, acc, 0, 0, 0);
            const float xm = xxm[mt & 1][ct * 16 + lrow];
            const unsigned int p = (unsigned int)(mt * 4 + ct);
            #pragma unroll
            for (int r = 0; r < 4; ++r) {
                float v = fmaf(acc[r], 2.f, xm);                     // score + 1000 (>0)
                unsigned int u = __float_as_uint(v);
                float t = __uint_as_float((u & 0xFFFFFF80u) | p);    // pos in low mantissa
                float nk[8];
                nk[0] = fmaxf(keys[r][0], t);
                #pragma unroll
                for (int j = 1; j < 8; ++j)
                    nk[j] = __builtin_amdgcn_fmed3f(t, keys[r][j - 1], keys[r][j]);
                #pragma unroll
                for (int j = 0; j < 8; ++j) keys[r][j] = nk[j];
            }
        }

        if (mt + 1 < 32) {
            #pragma unroll
            for (int k = 0; k < 4; ++k) {
                int G = G0 + k, row = G >> 4, g = G & 15;
                *(uint4*)&nxt[row * 136 + g * 8] = pr[k];
            }
            if (tid < 64) xxm[(mt + 1) & 1][tid] = pxv;
        }
        __syncthreads();
    }

    // dump keys: mK[row][lrow*8 + j], row = wave*16 + quad*4 + r   (32 KB <= 34816 B)
    float* mK = (float*)&P[0][0];
    const int mrow = wave * 16 + quad * 4;
    #pragma unroll
    for (int r = 0; r < 4; ++r) {
        float4 k0 = make_float4(keys[r][0], keys[r][1], keys[r][2], keys[r][3]);
        float4 k1 = make_float4(keys[r][4], keys[r][5], keys[r][6], keys[r][7]);
        *(float4*)&mK[(mrow + r) * 128 + lrow * 8]     = k0;
        *(float4*)&mK[(mrow + r) * 128 + lrow * 8 + 4] = k1;
    }
    __syncthreads();

    if (tid < 64) {
        float bk[NCH]; int bc[NCH];
        #pragma unroll
        for (int j = 0; j < NCH; ++j) { bk[j] = 0.f; bc[j] = 0; }
        const float* rowK = mK + tid * 128;
        for (int c = 0; c < 128; ++c) {
            int pos = (tid + c) & 127;
            float k = rowK[pos];
            if (k > bk[NCH - 1]) {
                int lr = pos >> 3;
                int p  = (int)(__float_as_uint(k) & 0x7Fu);
                int col = ((colT0 + (p >> 2)) << 6) + ((p & 3) << 4) + lr;
                bk[NCH - 1] = k; bc[NCH - 1] = col;
                #pragma unroll
                for (int j = NCH - 1; j > 0; --j) {
                    if (bk[j] > bk[j - 1]) {
                        float tk = bk[j]; bk[j] = bk[j - 1]; bk[j - 1] = tk;
                        int tc = bc[j]; bc[j] = bc[j - 1]; bc[j - 1] = tc;
                    }
                }
            }
        }
        int* co = cand + ((size_t)((b << 12) + n0 + tid)) * NCT + half * NCH;
        #pragma unroll
        for (int j = 0; j < NCH; ++j) co[j] = bc[j];
    }
}

// ---------------- Kernel 3: exact fp64 re-rank of 32 candidates + gather/max -> feat ----------------
__global__ __launch_bounds__(256) void rerank_kernel(const float* __restrict__ x,
                                                     const double* __restrict__ xxd,
                                                     const int* __restrict__ cand,
                                                     float* __restrict__ feat) {
    __shared__ double sc[4][NCT];
    __shared__ int    si[4][NCT];
    __shared__ int    sel[4][KNN];
    const int tid = threadIdx.x, wave = tid >> 6, lane = tid & 63;
    const size_t row = (size_t)blockIdx.x * 4 + wave;     // 0..32767
    const int b = (int)(row >> 12);
    const float* xb = x + (((size_t)b) << 12) * CIN;
    const float* xn = x + row * CIN;

    const int cidx = lane & 31, part = lane >> 5;
    int m = cand[row * NCT + cidx];
    {
        const float* xm = xb + (size_t)m * CIN;
        const float* xa = xn + part * 32;
        const float* xv = xm + part * 32;
        double d = 0.0;
        #pragma unroll
        for (int c4 = 0; c4 < 8; ++c4) {
            float4 a = *(const float4*)&xa[c4 * 4];
            float4 v = *(const float4*)&xv[c4 * 4];
            d = fma((double)a.x, (double)v.x, d);
            d = fma((double)a.y, (double)v.y, d);
            d = fma((double)a.z, (double)v.z, d);
            d = fma((double)a.w, (double)v.w, d);
        }
        d += __shfl_xor(d, 32);
        if (part == 0) {
            sc[wave][cidx] = 2.0 * d - xxd[(((size_t)b) << 12) + m];
            si[wave][cidx] = m;
        }
    }
    __syncthreads();

    if (lane == 0) {
        double fd[KNN]; int fi[KNN];
        #pragma unroll
        for (int j = 0; j < KNN; ++j) { fd[j] = -1.0e300; fi[j] = 0; }
        for (int c = 0; c < NCT; ++c) {
            double v = sc[wave][c];
            if (v > fd[KNN - 1]) {
                fd[KNN - 1] = v; fi[KNN - 1] = si[wave][c];
                #pragma unroll
                for (int j = KNN - 1; j > 0; --j) {
                    if (fd[j] > fd[j - 1]) {
                        double td = fd[j]; fd[j] = fd[j - 1]; fd[j - 1] = td;
                        int    ti = fi[j]; fi[j] = fi[j - 1]; fi[j - 1] = ti;
                    }
                }
            }
        }
        #pragma unroll
        for (int j = 0; j < KNN; ++j) sel[wave][j] = fi[j];
    }
    __syncthreads();

    float mx = -3.0e38f;
    #pragma unroll
    for (int j = 0; j < KNN; ++j)
        mx = fmaxf(mx, xb[(size_t)sel[wave][j] * CIN + lane]);
    feat[row * CIN + lane] = mx;
}

// ---------------- Kernel 4: conv (fp32 VALU) -> y + BN stats ----------------
__global__ __launch_bounds__(256) void conv_stats_kernel(const float* __restrict__ feat,
                                                         const float* __restrict__ W,
                                                         float* __restrict__ y,
                                                         float* __restrict__ st) {
    __shared__ float Wt[64 * 128];   // Wt[c][o]
    __shared__ float Fs[64 * 64];
    __shared__ float bs[128], bs2[128];
    const int tid = threadIdx.x;
    const int n0  = blockIdx.x * 64;

    for (int i = tid; i < 8192; i += 256) {
        int o = i >> 6, c = i & 63;
        Wt[c * 128 + o] = W[i];
    }
    for (int i = tid; i < 1024; i += 256)
        ((float4*)Fs)[i] = ((const float4*)(feat + (size_t)n0 * CIN))[i];
    if (tid < 128) { bs[tid] = 0.f; bs2[tid] = 0.f; }
    __syncthreads();

    const int og = tid & 31, rg = tid >> 5;
    float ts[4] = {0.f, 0.f, 0.f, 0.f}, ts2[4] = {0.f, 0.f, 0.f, 0.f};
    #pragma unroll
    for (int p = 0; p < 4; ++p) {
        const int r0 = p * 16 + rg * 2;
        float acc0[4] = {0.f, 0.f, 0.f, 0.f}, acc1[4] = {0.f, 0.f, 0.f, 0.f};
        for (int c = 0; c < 64; ++c) {
            float f0 = Fs[r0 * 64 + c], f1 = Fs[(r0 + 1) * 64 + c];
            #pragma unroll
            for (int j = 0; j < 4; ++j) {
                float w = Wt[c * 128 + og + 32 * j];
                acc0[j] += f0 * w; acc1[j] += f1 * w;
            }
        }
        #pragma unroll
        for (int j = 0; j < 4; ++j) {
            const int ch = og + 32 * j;
            y[(size_t)(n0 + r0)     * COUT + ch] = acc0[j];
            y[(size_t)(n0 + r0 + 1) * COUT + ch] = acc1[j];
            ts[j]  += acc0[j] + acc1[j];
            ts2[j] += acc0[j] * acc0[j] + acc1[j] * acc1[j];
        }
    }
    #pragma unroll
    for (int j = 0; j < 4; ++j) {
        atomicAdd(&bs [og + 32 * j], ts[j]);
        atomicAdd(&bs2[og + 32 * j], ts2[j]);
    }
    __syncthreads();
    if (tid < 128) {
        atomicAdd(&st[tid],       bs[tid]);
        atomicAdd(&st[128 + tid], bs2[tid]);
    }
}

// ---------------- Kernel 5: elementwise BN + LeakyReLU -> fp32 out ----------------
__global__ __launch_bounds__(256) void norm_out_kernel(const float* __restrict__ y,
                                                       const float* __restrict__ st,
                                                       const float* __restrict__ gamma,
                                                       const float* __restrict__ beta,
                                                       float* __restrict__ out) {
    size_t i = ((size_t)blockIdx.x * 256 + threadIdx.x) * 4;
    int c0 = (int)(i & 127);
    float4 v = *(const float4*)&y[i];
    float o[4];
    const float inv = 1.0f / (float)TOTROWS;
    #pragma unroll
    for (int j = 0; j < 4; ++j) {
        int c = c0 + j;
        float m  = st[c] * inv;
        float vr = st[128 + c] * inv - m * m;
        float sc = rsqrtf(vr + 1e-5f) * gamma[c];
        float t  = (((const float*)&v)[j] - m) * sc + beta[c];
        o[j] = (t >= 0.f) ? t : 0.01f * t;
    }
    *(float4*)&out[i] = make_float4(o[0], o[1], o[2], o[3]);
}

extern "C" void kernel_launch(void* const* d_in, const int* in_sizes, int n_in,
                              void* d_out, int out_size, void* d_ws, size_t ws_size,
                              hipStream_t stream) {
    (void)in_sizes; (void)n_in; (void)out_size; (void)ws_size;
    const float* x     = (const float*)d_in[0];
    const float* W     = (const float*)d_in[1];
    const float* gamma = (const float*)d_in[2];
    const float* beta  = (const float*)d_in[3];
    // d_in[4] is k == 8 (compile-time KNN)
    float* out = (float*)d_out;

    // workspace (~28.4 MB): xxf 128K | xxd 256K | cand 4M | feat 8M | xpack 16M (reused as y) | st 1K
    char*   ws    = (char*)d_ws;
    float*  xxf   = (float*)ws;
    double* xxd   = (double*)(ws + 131072);
    int*    cand  = (int*)(ws + 131072 + 262144);
    float*  feat  = (float*)(ws + 131072 + 262144 + 4194304);
    unsigned short* xpack = (unsigned short*)(ws + 131072 + 262144 + 4194304 + 8388608);
    float*  y     = (float*)xpack;   // xpack dead after knn_cand; y is 16 MB fp32
    float*  st    = (float*)(ws + 131072 + 262144 + 4194304 + 8388608 + 16777216);

    hipMemsetAsync(st, 0, 256 * sizeof(float), stream);
    prep_kernel      <<<TOTROWS * 8 / 256, 256, 0, stream>>>(x, xpack, xxf, xxd);
    knn_cand_kernel  <<<dim3(NPTS / 64, 2, BATCH), 256, 0, stream>>>(xpack, xxf, cand);
    rerank_kernel    <<<TOTROWS / 4, 256, 0, stream>>>(x, xxd, cand, feat);
    conv_stats_kernel<<<TOTROWS / 64, 256, 0, stream>>>(feat, W, y, st);
    norm_out_kernel  <<<(TOTROWS * COUT) / (256 * 4), 256, 0, stream>>>(y, st, gamma, beta, out);
}

// Round 9
// 458.204 us; speedup vs baseline: 1.0023x; 1.0023x over previous
//
#include <hip/hip_runtime.h>
#include <hip/hip_bf16.h>

#define NPTS 4096
#define CIN 64
#define COUT 128
#define BATCH 8
#define KNN 8
#define NCH 16              // candidates per column-half
#define NCT 32              // total candidates per row
#define TOTROWS (BATCH * NPTS)   // 32768

using short8 = __attribute__((ext_vector_type(8))) short;
using f32x4  = __attribute__((ext_vector_type(4))) float;

__device__ __forceinline__ unsigned short f2bf_rne(float f) {
    unsigned int u = __float_as_uint(f);
    unsigned int r = (u + 0x7fffu + ((u >> 16) & 1u)) >> 16;
    return (unsigned short)r;
}

// ---------------- Kernel 1: pack x -> bf16(RNE) rows (128B) + exact row norms ----------------
__global__ __launch_bounds__(256) void prep_kernel(const float* __restrict__ x,
                                                   unsigned short* __restrict__ xpack,
                                                   float* __restrict__ xxf,
                                                   double* __restrict__ xxd) {
    int i   = blockIdx.x * 256 + threadIdx.x;    // 0 .. 262143
    int row = i >> 3, g = i & 7;                 // 8 threads per row
    const float* src = x + (size_t)row * CIN + g * 8;
    float4 v0 = *(const float4*)src;
    float4 v1 = *(const float4*)(src + 4);
    float f[8] = {v0.x, v0.y, v0.z, v0.w, v1.x, v1.y, v1.z, v1.w};

    unsigned int h[8];
    double s = 0.0;
    #pragma unroll
    for (int j = 0; j < 8; ++j) {
        h[j] = (unsigned int)f2bf_rne(f[j]);
        s += (double)f[j] * (double)f[j];
    }
    uint4 hi;
    hi.x = h[0] | (h[1] << 16); hi.y = h[2] | (h[3] << 16);
    hi.z = h[4] | (h[5] << 16); hi.w = h[6] | (h[7] << 16);
    *(uint4*)&xpack[(size_t)row * 64 + g * 8] = hi;

    s += __shfl_xor(s, 1);
    s += __shfl_xor(s, 2);
    s += __shfl_xor(s, 4);
    if (g == 0) { xxf[row] = (float)s; xxd[row] = s; }
}

// ---------------- Kernel 2: bf16 MFMA scores -> u32-key pair-merge top-8/lane -> top-16/half ----------------
// key = bits(float(score + 1000)) with low 7 mantissa bits = stream position p = mt*4+ct.
// Positive floats => u32 order == float order. Truncation err 0.008 << rank8->16 margin ~6;
// bf16 score err <=~0.4 also << margin; rerank is exact fp64 regardless.
__global__ __launch_bounds__(256, 4) void knn_cand_kernel(const unsigned short* __restrict__ xpack,
                                                          const float* __restrict__ xxf,
                                                          int* __restrict__ cand) {
    // union: staging tiles (2 x 64 x 72 ushorts = 18432 B) vs merge keys (64*128 u32 = 32768 B)
    __shared__ __align__(16) unsigned char SMEM[32768];
    __shared__ float xxm[2][64];
    unsigned short* P0 = (unsigned short*)SMEM;            // tile buf 0
    unsigned short* P1 = (unsigned short*)(SMEM + 9216);   // tile buf 1
    unsigned int*   mK = (unsigned int*)SMEM;              // merge scratch (after loop)

    const int tid  = threadIdx.x;
    const int n0   = blockIdx.x * 64;
    const int half = blockIdx.y;
    const int b    = blockIdx.z;
    const int wave = tid >> 6;
    const int lane = tid & 63;
    const int lrow = lane & 15;
    const int quad = lane >> 4;
    const int colT0 = half * 32;                 // first 64-col tile of this half

    const unsigned short* xp = xpack + ((size_t)b << 12) * 64;

    // stage A tile (rows n0..n0+63): 512 x 16B chunks
    for (int G = tid; G < 512; G += 256) {
        int row = G >> 3, g = G & 7;
        *(uint4*)&P0[row * 72 + g * 8] = *(const uint4*)&xp[(size_t)(n0 + row) * 64 + g * 8];
    }
    __syncthreads();

    const int arow = (wave * 16 + lrow) * 72;
    short8 ah0 = *(const short8*)&P0[arow + quad * 8];
    short8 ah1 = *(const short8*)&P0[arow + 32 + quad * 8];

    // stage B tile 0 into P1: 512 chunks, 2 per thread
    {
        uint4 r0[2];
        const int G0 = tid * 2;
        #pragma unroll
        for (int k = 0; k < 2; ++k) {
            int G = G0 + k, row = G >> 3, g = G & 7;
            r0[k] = *(const uint4*)&xp[(size_t)(colT0 * 64 + row) * 64 + g * 8];
        }
        float xv = (tid < 64) ? (1000.f - xxf[(b << 12) + colT0 * 64 + tid]) : 0.f;
        #pragma unroll
        for (int k = 0; k < 2; ++k) {
            int G = G0 + k, row = G >> 3, g = G & 7;
            *(uint4*)&P1[row * 72 + g * 8] = r0[k];
        }
        if (tid < 64) xxm[0][tid] = xv;
    }
    __syncthreads();

    // per-lane: 4 row-lists (rows wave*16+quad*4+r), sorted-desc 8 u32 keys each
    unsigned int keys[4][8];
    #pragma unroll
    for (int r = 0; r < 4; ++r)
        #pragma unroll
        for (int j = 0; j < 8; ++j) keys[r][j] = 0u;

    for (int mt = 0; mt < 32; ++mt) {
        unsigned short* cur = (mt & 1) ? P0 : P1;
        unsigned short* nxt = (mt & 1) ? P1 : P0;

        uint4 pr[2]; float pxv = 0.f;
        const int G0 = tid * 2;
        if (mt + 1 < 32) {
            const int tnext = colT0 + mt + 1;
            #pragma unroll
            for (int k = 0; k < 2; ++k) {
                int G = G0 + k, row = G >> 3, g = G & 7;
                pr[k] = *(const uint4*)&xp[(size_t)(tnext * 64 + row) * 64 + g * 8];
            }
            if (tid < 64) pxv = 1000.f - xxf[(b << 12) + tnext * 64 + tid];
        }

        unsigned int pk[4];   // buffered keys from even ct
        #pragma unroll
        for (int ct = 0; ct < 4; ++ct) {
            const int brow = (ct * 16 + lrow) * 72;
            short8 bh0 = *(const short8*)&cur[brow + quad * 8];
            short8 bh1 = *(const short8*)&cur[brow + 32 + quad * 8];
            f32x4 acc = {0.f, 0.f, 0.f, 0.f};
            acc = __builtin_amdgcn_mfma_f32_16x16x32_bf16(ah0, bh0, acc, 0, 0, 0);
            acc = __builtin_amdgcn_mfma_f32_16x16x32_bf16(ah1, bh1, acc, 0, 0, 0);
            const float xm = xxm[mt & 1][ct * 16 + lrow];
            const unsigned int p = (unsigned int)(mt * 4 + ct);
            if ((ct & 1) == 0) {
                #pragma unroll
                for (int r = 0; r < 4; ++r) {
                    float v = fmaf(acc[r], 2.f, xm);                 // score + 1000 (>0)
                    pk[r] = (__float_as_uint(v) & 0xFFFFFF80u) | p;
                }
            } else {
                #pragma unroll
                for (int r = 0; r < 4; ++r) {
                    float v = fmaf(acc[r], 2.f, xm);
                    unsigned int k2 = (__float_as_uint(v) & 0xFFFFFF80u) | p;
                    unsigned int c0 = pk[r] > k2 ? pk[r] : k2;       // sorted pair
                    unsigned int c1 = pk[r] > k2 ? k2 : pk[r];
                    // merge-path: top-8 of (sorted8 ∪ {c0,c1})
                    unsigned int* K = keys[r];
                    unsigned int n0k = K[0] > c0 ? K[0] : c0;
                    unsigned int m10 = K[0] < c0 ? K[0] : c0;
                    unsigned int n1  = K[1] > m10 ? K[1] : m10; n1 = n1 > c1 ? n1 : c1;
                    unsigned int nk[8];
                    nk[0] = n0k; nk[1] = n1;
                    #pragma unroll
                    for (int j = 2; j < 8; ++j) {
                        unsigned int t1 = K[j - 1] < c0 ? K[j - 1] : c0;
                        unsigned int t2 = K[j - 2] < c1 ? K[j - 2] : c1;
                        unsigned int mx = t1 > t2 ? t1 : t2;
                        nk[j] = K[j] > mx ? K[j] : mx;
                    }
                    #pragma unroll
                    for (int j = 0; j < 8; ++j) K[j] = nk[j];
                }
            }
        }

        if (mt + 1 < 32) {
            #pragma unroll
            for (int k = 0; k < 2; ++k) {
                int G = G0 + k, row = G >> 3, g = G & 7;
                *(uint4*)&nxt[row * 72 + g * 8] = pr[k];
            }
            if (tid < 64) xxm[(mt + 1) & 1][tid] = pxv;
        }
        __syncthreads();
    }

    // dump keys: mK[row][lrow*8 + j], row = wave*16 + quad*4 + r   (32 KB)
    const int mrow = wave * 16 + quad * 4;
    #pragma unroll
    for (int r = 0; r < 4; ++r) {
        uint4 k0 = make_uint4(keys[r][0], keys[r][1], keys[r][2], keys[r][3]);
        uint4 k1 = make_uint4(keys[r][4], keys[r][5], keys[r][6], keys[r][7]);
        *(uint4*)&mK[(mrow + r) * 128 + lrow * 8]     = k0;
        *(uint4*)&mK[(mrow + r) * 128 + lrow * 8 + 4] = k1;
    }
    __syncthreads();

    if (tid < 64) {
        unsigned int bk[NCH]; int bc[NCH];
        #pragma unroll
        for (int j = 0; j < NCH; ++j) { bk[j] = 0u; bc[j] = 0; }
        const unsigned int* rowK = mK + tid * 128;
        for (int c = 0; c < 128; ++c) {
            int pos = (tid + c) & 127;
            unsigned int k = rowK[pos];
            if (k > bk[NCH - 1]) {
                int lr = pos >> 3;
                int p  = (int)(k & 0x7Fu);
                int col = ((colT0 + (p >> 2)) << 6) + ((p & 3) << 4) + lr;
                bk[NCH - 1] = k; bc[NCH - 1] = col;
                #pragma unroll
                for (int j = NCH - 1; j > 0; --j) {
                    if (bk[j] > bk[j - 1]) {
                        unsigned int tk = bk[j]; bk[j] = bk[j - 1]; bk[j - 1] = tk;
                        int tc = bc[j]; bc[j] = bc[j - 1]; bc[j - 1] = tc;
                    }
                }
            }
        }
        int* co = cand + ((size_t)((b << 12) + n0 + tid)) * NCT + half * NCH;
        #pragma unroll
        for (int j = 0; j < NCH; ++j) co[j] = bc[j];
    }
}

// ---------------- Kernel 3: exact fp64 re-rank of 32 candidates + gather/max -> feat ----------------
__global__ __launch_bounds__(256) void rerank_kernel(const float* __restrict__ x,
                                                     const double* __restrict__ xxd,
                                                     const int* __restrict__ cand,
                                                     float* __restrict__ feat) {
    __shared__ double sc[4][NCT];
    __shared__ int    si[4][NCT];
    __shared__ int    sel[4][KNN];
    const int tid = threadIdx.x, wave = tid >> 6, lane = tid & 63;
    const size_t row = (size_t)blockIdx.x * 4 + wave;     // 0..32767
    const int b = (int)(row >> 12);
    const float* xb = x + (((size_t)b) << 12) * CIN;
    const float* xn = x + row * CIN;

    const int cidx = lane & 31, part = lane >> 5;
    int m = cand[row * NCT + cidx];
    {
        const float* xm = xb + (size_t)m * CIN;
        const float* xa = xn + part * 32;
        const float* xv = xm + part * 32;
        double d = 0.0;
        #pragma unroll
        for (int c4 = 0; c4 < 8; ++c4) {
            float4 a = *(const float4*)&xa[c4 * 4];
            float4 v = *(const float4*)&xv[c4 * 4];
            d = fma((double)a.x, (double)v.x, d);
            d = fma((double)a.y, (double)v.y, d);
            d = fma((double)a.z, (double)v.z, d);
            d = fma((double)a.w, (double)v.w, d);
        }
        d += __shfl_xor(d, 32);
        if (part == 0) {
            sc[wave][cidx] = 2.0 * d - xxd[(((size_t)b) << 12) + m];
            si[wave][cidx] = m;
        }
    }
    __syncthreads();

    if (lane == 0) {
        double fd[KNN]; int fi[KNN];
        #pragma unroll
        for (int j = 0; j < KNN; ++j) { fd[j] = -1.0e300; fi[j] = 0; }
        for (int c = 0; c < NCT; ++c) {
            double v = sc[wave][c];
            if (v > fd[KNN - 1]) {
                fd[KNN - 1] = v; fi[KNN - 1] = si[wave][c];
                #pragma unroll
                for (int j = KNN - 1; j > 0; --j) {
                    if (fd[j] > fd[j - 1]) {
                        double td = fd[j]; fd[j] = fd[j - 1]; fd[j - 1] = td;
                        int    ti = fi[j]; fi[j] = fi[j - 1]; fi[j - 1] = ti;
                    }
                }
            }
        }
        #pragma unroll
        for (int j = 0; j < KNN; ++j) sel[wave][j] = fi[j];
    }
    __syncthreads();

    float mx = -3.0e38f;
    #pragma unroll
    for (int j = 0; j < KNN; ++j)
        mx = fmaxf(mx, xb[(size_t)sel[wave][j] * CIN + lane]);
    feat[row * CIN + lane] = mx;
}

// ---------------- Kernel 4: conv (fp32 VALU) -> y + BN stats ----------------
__global__ __launch_bounds__(256) void conv_stats_kernel(const float* __restrict__ feat,
                                                         const float* __restrict__ W,
                                                         float* __restrict__ y,
                                                         float* __restrict__ st) {
    __shared__ float Wt[64 * 128];   // Wt[c][o]
    __shared__ float Fs[64 * 64];
    __shared__ float bs[128], bs2[128];
    const int tid = threadIdx.x;
    const int n0  = blockIdx.x * 64;

    for (int i = tid; i < 8192; i += 256) {
        int o = i >> 6, c = i & 63;
        Wt[c * 128 + o] = W[i];
    }
    for (int i = tid; i < 1024; i += 256)
        ((float4*)Fs)[i] = ((const float4*)(feat + (size_t)n0 * CIN))[i];
    if (tid < 128) { bs[tid] = 0.f; bs2[tid] = 0.f; }
    __syncthreads();

    const int og = tid & 31, rg = tid >> 5;
    float ts[4] = {0.f, 0.f, 0.f, 0.f}, ts2[4] = {0.f, 0.f, 0.f, 0.f};
    #pragma unroll
    for (int p = 0; p < 4; ++p) {
        const int r0 = p * 16 + rg * 2;
        float acc0[4] = {0.f, 0.f, 0.f, 0.f}, acc1[4] = {0.f, 0.f, 0.f, 0.f};
        for (int c = 0; c < 64; ++c) {
            float f0 = Fs[r0 * 64 + c], f1 = Fs[(r0 + 1) * 64 + c];
            #pragma unroll
            for (int j = 0; j < 4; ++j) {
                float w = Wt[c * 128 + og + 32 * j];
                acc0[j] += f0 * w; acc1[j] += f1 * w;
            }
        }
        #pragma unroll
        for (int j = 0; j < 4; ++j) {
            const int ch = og + 32 * j;
            y[(size_t)(n0 + r0)     * COUT + ch] = acc0[j];
            y[(size_t)(n0 + r0 + 1) * COUT + ch] = acc1[j];
            ts[j]  += acc0[j] + acc1[j];
            ts2[j] += acc0[j] * acc0[j] + acc1[j] * acc1[j];
        }
    }
    #pragma unroll
    for (int j = 0; j < 4; ++j) {
        atomicAdd(&bs [og + 32 * j], ts[j]);
        atomicAdd(&bs2[og + 32 * j], ts2[j]);
    }
    __syncthreads();
    if (tid < 128) {
        atomicAdd(&st[tid],       bs[tid]);
        atomicAdd(&st[128 + tid], bs2[tid]);
    }
}

// ---------------- Kernel 5: elementwise BN + LeakyReLU -> fp32 out ----------------
__global__ __launch_bounds__(256) void norm_out_kernel(const float* __restrict__ y,
                                                       const float* __restrict__ st,
                                                       const float* __restrict__ gamma,
                                                       const float* __restrict__ beta,
                                                       float* __restrict__ out) {
    size_t i = ((size_t)blockIdx.x * 256 + threadIdx.x) * 4;
    int c0 = (int)(i & 127);
    float4 v = *(const float4*)&y[i];
    float o[4];
    const float inv = 1.0f / (float)TOTROWS;
    #pragma unroll
    for (int j = 0; j < 4; ++j) {
        int c = c0 + j;
        float m  = st[c] * inv;
        float vr = st[128 + c] * inv - m * m;
        float sc = rsqrtf(vr + 1e-5f) * gamma[c];
        float t  = (((const float*)&v)[j] - m) * sc + beta[c];
        o[j] = (t >= 0.f) ? t : 0.01f * t;
    }
    *(float4*)&out[i] = make_float4(o[0], o[1], o[2], o[3]);
}

extern "C" void kernel_launch(void* const* d_in, const int* in_sizes, int n_in,
                              void* d_out, int out_size, void* d_ws, size_t ws_size,
                              hipStream_t stream) {
    (void)in_sizes; (void)n_in; (void)out_size; (void)ws_size;
    const float* x     = (const float*)d_in[0];
    const float* W     = (const float*)d_in[1];
    const float* gamma = (const float*)d_in[2];
    const float* beta  = (const float*)d_in[3];
    // d_in[4] is k == 8 (compile-time KNN)
    float* out = (float*)d_out;

    // workspace (~28.4 MB): xxf 128K | xxd 256K | cand 4M | feat 8M | region 16M (xpack 4M, reused as y 16M) | st
    char*   ws    = (char*)d_ws;
    float*  xxf   = (float*)ws;
    double* xxd   = (double*)(ws + 131072);
    int*    cand  = (int*)(ws + 131072 + 262144);
    float*  feat  = (float*)(ws + 131072 + 262144 + 4194304);
    unsigned short* xpack = (unsigned short*)(ws + 131072 + 262144 + 4194304 + 8388608);
    float*  y     = (float*)xpack;   // xpack (4 MB used) dead after knn_cand; y is 16 MB fp32
    float*  st    = (float*)(ws + 131072 + 262144 + 4194304 + 8388608 + 16777216);

    hipMemsetAsync(st, 0, 256 * sizeof(float), stream);
    prep_kernel      <<<TOTROWS * 8 / 256, 256, 0, stream>>>(x, xpack, xxf, xxd);
    knn_cand_kernel  <<<dim3(NPTS / 64, 2, BATCH), 256, 0, stream>>>(xpack, xxf, cand);
    rerank_kernel    <<<TOTROWS / 4, 256, 0, stream>>>(x, xxd, cand, feat);
    conv_stats_kernel<<<TOTROWS / 64, 256, 0, stream>>>(feat, W, y, st);
    norm_out_kernel  <<<(TOTROWS * COUT) / (256 * 4), 256, 0, stream>>>(y, st, gamma, beta, out);
}

// Round 10
// 389.593 us; speedup vs baseline: 1.1788x; 1.1761x over previous
//
#include <hip/hip_runtime.h>
#include <hip/hip_bf16.h>

#define NPTS 4096
#define CIN 64
#define COUT 128
#define BATCH 8
#define KNN 8
#define NCH 12              // candidates per column-half
#define NCT 24              // total candidates per row
#define TOTROWS (BATCH * NPTS)   // 32768

using short8 = __attribute__((ext_vector_type(8))) short;
using f32x4  = __attribute__((ext_vector_type(4))) float;

__device__ __forceinline__ unsigned short f2bf_rne(float f) {
    unsigned int u = __float_as_uint(f);
    unsigned int r = (u + 0x7fffu + ((u >> 16) & 1u)) >> 16;
    return (unsigned short)r;
}

// ---------------- Kernel 1: pack x -> bf16(RNE) rows (128B) + exact row norms ----------------
__global__ __launch_bounds__(256) void prep_kernel(const float* __restrict__ x,
                                                   unsigned short* __restrict__ xpack,
                                                   float* __restrict__ xxf,
                                                   double* __restrict__ xxd) {
    int i   = blockIdx.x * 256 + threadIdx.x;    // 0 .. 262143
    int row = i >> 3, g = i & 7;                 // 8 threads per row
    const float* src = x + (size_t)row * CIN + g * 8;
    float4 v0 = *(const float4*)src;
    float4 v1 = *(const float4*)(src + 4);
    float f[8] = {v0.x, v0.y, v0.z, v0.w, v1.x, v1.y, v1.z, v1.w};

    unsigned int h[8];
    double s = 0.0;
    #pragma unroll
    for (int j = 0; j < 8; ++j) {
        h[j] = (unsigned int)f2bf_rne(f[j]);
        s += (double)f[j] * (double)f[j];
    }
    uint4 hi;
    hi.x = h[0] | (h[1] << 16); hi.y = h[2] | (h[3] << 16);
    hi.z = h[4] | (h[5] << 16); hi.w = h[6] | (h[7] << 16);
    *(uint4*)&xpack[(size_t)row * 64 + g * 8] = hi;

    s += __shfl_xor(s, 1);
    s += __shfl_xor(s, 2);
    s += __shfl_xor(s, 4);
    if (g == 0) { xxf[row] = (float)s; xxd[row] = s; }
}

// ---------------- Kernel 2: bf16 MFMA scores -> u32-key serial-insert top-8/lane -> top-12/half ----------------
// key = bits(float(score + 1000)) with low 7 mantissa bits = stream position p = mt*4+ct.
// Positive floats => u32 order == float order. bf16 score err <=~0.26 + trunc 0.008 << rank8->12
// margin (~4 gaps x ~1.5); any true top-8 elem ranks <=8 within its half; rerank is exact fp64.
__global__ __launch_bounds__(256) void knn_cand_kernel(const unsigned short* __restrict__ xpack,
                                                       const float* __restrict__ xxf,
                                                       int* __restrict__ cand) {
    // union: staging tiles (2 x 64 x 72 ushorts = 18432 B) vs merge keys (64*128 u32 = 32768 B)
    __shared__ __align__(16) unsigned char SMEM[32768];
    __shared__ float xxm[2][64];
    unsigned short* P0 = (unsigned short*)SMEM;            // tile buf 0
    unsigned short* P1 = (unsigned short*)(SMEM + 9216);   // tile buf 1
    unsigned int*   mK = (unsigned int*)SMEM;              // merge scratch (after loop)

    const int tid  = threadIdx.x;
    const int n0   = blockIdx.x * 64;
    const int half = blockIdx.y;
    const int b    = blockIdx.z;
    const int wave = tid >> 6;
    const int lane = tid & 63;
    const int lrow = lane & 15;
    const int quad = lane >> 4;
    const int colT0 = half * 32;                 // first 64-col tile of this half

    const unsigned short* xp = xpack + ((size_t)b << 12) * 64;

    // stage A tile (rows n0..n0+63): 512 x 16B chunks
    for (int G = tid; G < 512; G += 256) {
        int row = G >> 3, g = G & 7;
        *(uint4*)&P0[row * 72 + g * 8] = *(const uint4*)&xp[(size_t)(n0 + row) * 64 + g * 8];
    }
    __syncthreads();

    const int arow = (wave * 16 + lrow) * 72;
    short8 ah0 = *(const short8*)&P0[arow + quad * 8];
    short8 ah1 = *(const short8*)&P0[arow + 32 + quad * 8];

    // stage B tile 0 into P1: 512 chunks, 2 per thread
    {
        uint4 r0[2];
        const int G0 = tid * 2;
        #pragma unroll
        for (int k = 0; k < 2; ++k) {
            int G = G0 + k, row = G >> 3, g = G & 7;
            r0[k] = *(const uint4*)&xp[(size_t)(colT0 * 64 + row) * 64 + g * 8];
        }
        float xv = (tid < 64) ? (1000.f - xxf[(b << 12) + colT0 * 64 + tid]) : 0.f;
        #pragma unroll
        for (int k = 0; k < 2; ++k) {
            int G = G0 + k, row = G >> 3, g = G & 7;
            *(uint4*)&P1[row * 72 + g * 8] = r0[k];
        }
        if (tid < 64) xxm[0][tid] = xv;
    }
    __syncthreads();

    // per-lane: 4 row-lists (rows wave*16+quad*4+r), sorted-desc 8 u32 keys each
    unsigned int keys[4][8];
    #pragma unroll
    for (int r = 0; r < 4; ++r)
        #pragma unroll
        for (int j = 0; j < 8; ++j) keys[r][j] = 0u;

    for (int mt = 0; mt < 32; ++mt) {
        unsigned short* cur = (mt & 1) ? P0 : P1;
        unsigned short* nxt = (mt & 1) ? P1 : P0;

        uint4 pr[2]; float pxv = 0.f;
        const int G0 = tid * 2;
        if (mt + 1 < 32) {
            const int tnext = colT0 + mt + 1;
            #pragma unroll
            for (int k = 0; k < 2; ++k) {
                int G = G0 + k, row = G >> 3, g = G & 7;
                pr[k] = *(const uint4*)&xp[(size_t)(tnext * 64 + row) * 64 + g * 8];
            }
            if (tid < 64) pxv = 1000.f - xxf[(b << 12) + tnext * 64 + tid];
        }

        #pragma unroll
        for (int ct = 0; ct < 4; ++ct) {
            const int brow = (ct * 16 + lrow) * 72;
            short8 bh0 = *(const short8*)&cur[brow + quad * 8];
            short8 bh1 = *(const short8*)&cur[brow + 32 + quad * 8];
            f32x4 acc = {0.f, 0.f, 0.f, 0.f};
            acc = __builtin_amdgcn_mfma_f32_16x16x32_bf16(ah0, bh0, acc, 0, 0, 0);
            acc = __builtin_amdgcn_mfma_f32_16x16x32_bf16(ah1, bh1, acc, 0, 0, 0);
            const float xm = xxm[mt & 1][ct * 16 + lrow];
            const unsigned int p = (unsigned int)(mt * 4 + ct);
            #pragma unroll
            for (int r = 0; r < 4; ++r) {
                float v = fmaf(acc[r], 2.f, xm);                     // score + 1000 (>0)
                unsigned int t = (__float_as_uint(v) & 0xFFFFFF80u) | p;
                // serial sorted insert (desc) — proven R7 codegen
                #pragma unroll
                for (int j = 0; j < 8; ++j) {
                    unsigned int mx = keys[r][j] > t ? keys[r][j] : t;
                    unsigned int mn = keys[r][j] > t ? t : keys[r][j];
                    keys[r][j] = mx; t = mn;
                }
            }
        }

        if (mt + 1 < 32) {
            #pragma unroll
            for (int k = 0; k < 2; ++k) {
                int G = G0 + k, row = G >> 3, g = G & 7;
                *(uint4*)&nxt[row * 72 + g * 8] = pr[k];
            }
            if (tid < 64) xxm[(mt + 1) & 1][tid] = pxv;
        }
        __syncthreads();
    }

    // dump keys: mK[row][lrow*8 + j], row = wave*16 + quad*4 + r   (32 KB)
    const int mrow = wave * 16 + quad * 4;
    #pragma unroll
    for (int r = 0; r < 4; ++r) {
        uint4 k0 = make_uint4(keys[r][0], keys[r][1], keys[r][2], keys[r][3]);
        uint4 k1 = make_uint4(keys[r][4], keys[r][5], keys[r][6], keys[r][7]);
        *(uint4*)&mK[(mrow + r) * 128 + lrow * 8]     = k0;
        *(uint4*)&mK[(mrow + r) * 128 + lrow * 8 + 4] = k1;
    }
    __syncthreads();

    if (tid < 64) {
        unsigned int bk[NCH]; int bc[NCH];
        #pragma unroll
        for (int j = 0; j < NCH; ++j) { bk[j] = 0u; bc[j] = 0; }
        const unsigned int* rowK = mK + tid * 128;
        for (int c = 0; c < 128; ++c) {
            int pos = (tid + c) & 127;
            unsigned int k = rowK[pos];
            if (k > bk[NCH - 1]) {
                int lr = pos >> 3;
                int p  = (int)(k & 0x7Fu);
                int col = ((colT0 + (p >> 2)) << 6) + ((p & 3) << 4) + lr;
                bk[NCH - 1] = k; bc[NCH - 1] = col;
                #pragma unroll
                for (int j = NCH - 1; j > 0; --j) {
                    if (bk[j] > bk[j - 1]) {
                        unsigned int tk = bk[j]; bk[j] = bk[j - 1]; bk[j - 1] = tk;
                        int tc = bc[j]; bc[j] = bc[j - 1]; bc[j - 1] = tc;
                    }
                }
            }
        }
        int* co = cand + ((size_t)((b << 12) + n0 + tid)) * NCT + half * NCH;
        #pragma unroll
        for (int j = 0; j < NCH; ++j) co[j] = bc[j];
    }
}

// ---------------- Kernel 3: exact fp64 re-rank of 24 candidates + gather/max -> feat ----------------
__global__ __launch_bounds__(256) void rerank_kernel(const float* __restrict__ x,
                                                     const double* __restrict__ xxd,
                                                     const int* __restrict__ cand,
                                                     float* __restrict__ feat) {
    __shared__ double sc[4][NCT];
    __shared__ int    si[4][NCT];
    __shared__ int    sel[4][KNN];
    const int tid = threadIdx.x, wave = tid >> 6, lane = tid & 63;
    const size_t row = (size_t)blockIdx.x * 4 + wave;     // 0..32767
    const int b = (int)(row >> 12);
    const float* xb = x + (((size_t)b) << 12) * CIN;
    const float* xn = x + row * CIN;

    const int cidx = lane & 31, part = lane >> 5;
    if (cidx < NCT) {
        int m = cand[row * NCT + cidx];
        const float* xm = xb + (size_t)m * CIN;
        const float* xa = xn + part * 32;
        const float* xv = xm + part * 32;
        double d = 0.0;
        #pragma unroll
        for (int c4 = 0; c4 < 8; ++c4) {
            float4 a = *(const float4*)&xa[c4 * 4];
            float4 v = *(const float4*)&xv[c4 * 4];
            d = fma((double)a.x, (double)v.x, d);
            d = fma((double)a.y, (double)v.y, d);
            d = fma((double)a.z, (double)v.z, d);
            d = fma((double)a.w, (double)v.w, d);
        }
        d += __shfl_xor(d, 32);
        if (part == 0) {
            sc[wave][cidx] = 2.0 * d - xxd[(((size_t)b) << 12) + m];
            si[wave][cidx] = m;
        }
    }
    __syncthreads();

    if (lane == 0) {
        double fd[KNN]; int fi[KNN];
        #pragma unroll
        for (int j = 0; j < KNN; ++j) { fd[j] = -1.0e300; fi[j] = 0; }
        for (int c = 0; c < NCT; ++c) {
            double v = sc[wave][c];
            if (v > fd[KNN - 1]) {
                fd[KNN - 1] = v; fi[KNN - 1] = si[wave][c];
                #pragma unroll
                for (int j = KNN - 1; j > 0; --j) {
                    if (fd[j] > fd[j - 1]) {
                        double td = fd[j]; fd[j] = fd[j - 1]; fd[j - 1] = td;
                        int    ti = fi[j]; fi[j] = fi[j - 1]; fi[j - 1] = ti;
                    }
                }
            }
        }
        #pragma unroll
        for (int j = 0; j < KNN; ++j) sel[wave][j] = fi[j];
    }
    __syncthreads();

    float mx = -3.0e38f;
    #pragma unroll
    for (int j = 0; j < KNN; ++j)
        mx = fmaxf(mx, xb[(size_t)sel[wave][j] * CIN + lane]);
    feat[row * CIN + lane] = mx;
}

// ---------------- Kernel 4: conv (fp32 VALU) -> y + BN stats ----------------
__global__ __launch_bounds__(256) void conv_stats_kernel(const float* __restrict__ feat,
                                                         const float* __restrict__ W,
                                                         float* __restrict__ y,
                                                         float* __restrict__ st) {
    __shared__ float Wt[64 * 128];   // Wt[c][o]
    __shared__ float Fs[64 * 64];
    __shared__ float bs[128], bs2[128];
    const int tid = threadIdx.x;
    const int n0  = blockIdx.x * 64;

    for (int i = tid; i < 8192; i += 256) {
        int o = i >> 6, c = i & 63;
        Wt[c * 128 + o] = W[i];
    }
    for (int i = tid; i < 1024; i += 256)
        ((float4*)Fs)[i] = ((const float4*)(feat + (size_t)n0 * CIN))[i];
    if (tid < 128) { bs[tid] = 0.f; bs2[tid] = 0.f; }
    __syncthreads();

    const int og = tid & 31, rg = tid >> 5;
    float ts[4] = {0.f, 0.f, 0.f, 0.f}, ts2[4] = {0.f, 0.f, 0.f, 0.f};
    #pragma unroll
    for (int p = 0; p < 4; ++p) {
        const int r0 = p * 16 + rg * 2;
        float acc0[4] = {0.f, 0.f, 0.f, 0.f}, acc1[4] = {0.f, 0.f, 0.f, 0.f};
        for (int c = 0; c < 64; ++c) {
            float f0 = Fs[r0 * 64 + c], f1 = Fs[(r0 + 1) * 64 + c];
            #pragma unroll
            for (int j = 0; j < 4; ++j) {
                float w = Wt[c * 128 + og + 32 * j];
                acc0[j] += f0 * w; acc1[j] += f1 * w;
            }
        }
        #pragma unroll
        for (int j = 0; j < 4; ++j) {
            const int ch = og + 32 * j;
            y[(size_t)(n0 + r0)     * COUT + ch] = acc0[j];
            y[(size_t)(n0 + r0 + 1) * COUT + ch] = acc1[j];
            ts[j]  += acc0[j] + acc1[j];
            ts2[j] += acc0[j] * acc0[j] + acc1[j] * acc1[j];
        }
    }
    #pragma unroll
    for (int j = 0; j < 4; ++j) {
        atomicAdd(&bs [og + 32 * j], ts[j]);
        atomicAdd(&bs2[og + 32 * j], ts2[j]);
    }
    __syncthreads();
    if (tid < 128) {
        atomicAdd(&st[tid],       bs[tid]);
        atomicAdd(&st[128 + tid], bs2[tid]);
    }
}

// ---------------- Kernel 5: elementwise BN + LeakyReLU -> fp32 out ----------------
__global__ __launch_bounds__(256) void norm_out_kernel(const float* __restrict__ y,
                                                       const float* __restrict__ st,
                                                       const float* __restrict__ gamma,
                                                       const float* __restrict__ beta,
                                                       float* __restrict__ out) {
    size_t i = ((size_t)blockIdx.x * 256 + threadIdx.x) * 4;
    int c0 = (int)(i & 127);
    float4 v = *(const float4*)&y[i];
    float o[4];
    const float inv = 1.0f / (float)TOTROWS;
    #pragma unroll
    for (int j = 0; j < 4; ++j) {
        int c = c0 + j;
        float m  = st[c] * inv;
        float vr = st[128 + c] * inv - m * m;
        float sc = rsqrtf(vr + 1e-5f) * gamma[c];
        float t  = (((const float*)&v)[j] - m) * sc + beta[c];
        o[j] = (t >= 0.f) ? t : 0.01f * t;
    }
    *(float4*)&out[i] = make_float4(o[0], o[1], o[2], o[3]);
}

extern "C" void kernel_launch(void* const* d_in, const int* in_sizes, int n_in,
                              void* d_out, int out_size, void* d_ws, size_t ws_size,
                              hipStream_t stream) {
    (void)in_sizes; (void)n_in; (void)out_size; (void)ws_size;
    const float* x     = (const float*)d_in[0];
    const float* W     = (const float*)d_in[1];
    const float* gamma = (const float*)d_in[2];
    const float* beta  = (const float*)d_in[3];
    // d_in[4] is k == 8 (compile-time KNN)
    float* out = (float*)d_out;

    // workspace (~28.4 MB): xxf 128K | xxd 256K | cand 4M | feat 8M | region 16M (xpack 4M, reused as y 16M) | st
    char*   ws    = (char*)d_ws;
    float*  xxf   = (float*)ws;
    double* xxd   = (double*)(ws + 131072);
    int*    cand  = (int*)(ws + 131072 + 262144);
    float*  feat  = (float*)(ws + 131072 + 262144 + 4194304);
    unsigned short* xpack = (unsigned short*)(ws + 131072 + 262144 + 4194304 + 8388608);
    float*  y     = (float*)xpack;   // xpack (4 MB used) dead after knn_cand; y is 16 MB fp32
    float*  st    = (float*)(ws + 131072 + 262144 + 4194304 + 8388608 + 16777216);

    hipMemsetAsync(st, 0, 256 * sizeof(float), stream);
    prep_kernel      <<<TOTROWS * 8 / 256, 256, 0, stream>>>(x, xpack, xxf, xxd);
    knn_cand_kernel  <<<dim3(NPTS / 64, 2, BATCH), 256, 0, stream>>>(xpack, xxf, cand);
    rerank_kernel    <<<TOTROWS / 4, 256, 0, stream>>>(x, xxd, cand, feat);
    conv_stats_kernel<<<TOTROWS / 64, 256, 0, stream>>>(feat, W, y, st);
    norm_out_kernel  <<<(TOTROWS * COUT) / (256 * 4), 256, 0, stream>>>(y, st, gamma, beta, out);
}

// Round 11
// 361.177 us; speedup vs baseline: 1.2715x; 1.0787x over previous
//
#include <hip/hip_runtime.h>
#include <hip/hip_bf16.h>

#define NPTS 4096
#define CIN 64
#define COUT 128
#define BATCH 8
#define KNN 8
#define NCH 12              // candidates per column-half
#define NCT 24              // total candidates per row
#define TOTROWS (BATCH * NPTS)   // 32768

using short8 = __attribute__((ext_vector_type(8))) short;
using f32x4  = __attribute__((ext_vector_type(4))) float;

__device__ __forceinline__ unsigned short f2bf_rne(float f) {
    unsigned int u = __float_as_uint(f);
    unsigned int r = (u + 0x7fffu + ((u >> 16) & 1u)) >> 16;
    return (unsigned short)r;
}

// ---------------- Kernel 1: pack x -> bf16(RNE) rows (128B) + norms (xxn = 1000-xx fp32, xxd fp64) ----------------
__global__ __launch_bounds__(256) void prep_kernel(const float* __restrict__ x,
                                                   unsigned short* __restrict__ xpack,
                                                   float* __restrict__ xxn,
                                                   double* __restrict__ xxd) {
    int i   = blockIdx.x * 256 + threadIdx.x;    // 0 .. 262143
    int row = i >> 3, g = i & 7;                 // 8 threads per row
    const float* src = x + (size_t)row * CIN + g * 8;
    float4 v0 = *(const float4*)src;
    float4 v1 = *(const float4*)(src + 4);
    float f[8] = {v0.x, v0.y, v0.z, v0.w, v1.x, v1.y, v1.z, v1.w};

    unsigned int h[8];
    double s = 0.0;
    #pragma unroll
    for (int j = 0; j < 8; ++j) {
        h[j] = (unsigned int)f2bf_rne(f[j]);
        s += (double)f[j] * (double)f[j];
    }
    uint4 hi;
    hi.x = h[0] | (h[1] << 16); hi.y = h[2] | (h[3] << 16);
    hi.z = h[4] | (h[5] << 16); hi.w = h[6] | (h[7] << 16);
    *(uint4*)&xpack[(size_t)row * 64 + g * 8] = hi;

    s += __shfl_xor(s, 1);
    s += __shfl_xor(s, 2);
    s += __shfl_xor(s, 4);
    if (g == 0) { xxn[row] = 1000.f - (float)s; xxd[row] = s; }
}

// ---------------- Kernel 2: bf16 MFMA scores (direct-global fragments, no LDS staging/barriers) ----------------
// key = bits(float(score+1000)) with low 7 mantissa bits = chunk position p (0..127).
// col = half*2048 + p*16 + lrow. Per-lane 8-deep sorted u32 lists (4 rows) -> block merge -> top-12/half.
// bf16 score err + 0.008 trunc << rank8->12 margin; rerank is exact fp64.
__global__ __launch_bounds__(256) void knn_cand_kernel(const unsigned short* __restrict__ xpack,
                                                       const float* __restrict__ xxn,
                                                       int* __restrict__ cand) {
    __shared__ unsigned int mK[64 * 128];   // 32 KB merge scratch

    const int tid  = threadIdx.x;
    const int n0   = blockIdx.x * 64;
    const int half = blockIdx.y;
    const int b    = blockIdx.z;
    const int wave = tid >> 6;
    const int lane = tid & 63;
    const int lrow = lane & 15;
    const int quad = lane >> 4;

    const unsigned short* xp = xpack + ((size_t)b << 12) * 64;
    const float* xnn = xxn + (b << 12);

    // A fragments: direct global load (coalesced 2 KB per wave)
    const int arow = n0 + wave * 16 + lrow;
    short8 ah0 = *(const short8*)&xp[arow * 64 + quad * 8];
    short8 ah1 = *(const short8*)&xp[arow * 64 + 32 + quad * 8];

    unsigned int keys[4][8];
    #pragma unroll
    for (int r = 0; r < 4; ++r)
        #pragma unroll
        for (int j = 0; j < 8; ++j) keys[r][j] = 0u;

    const int rbase = half * 2048 + lrow;
    #pragma unroll 2
    for (int p = 0; p < 128; ++p) {
        const int row0 = rbase + p * 16;
        short8 bh0 = *(const short8*)&xp[row0 * 64 + quad * 8];
        short8 bh1 = *(const short8*)&xp[row0 * 64 + 32 + quad * 8];
        const float xm = xnn[row0];
        f32x4 acc = {0.f, 0.f, 0.f, 0.f};
        acc = __builtin_amdgcn_mfma_f32_16x16x32_bf16(ah0, bh0, acc, 0, 0, 0);
        acc = __builtin_amdgcn_mfma_f32_16x16x32_bf16(ah1, bh1, acc, 0, 0, 0);
        #pragma unroll
        for (int r = 0; r < 4; ++r) {
            float v = fmaf(acc[r], 2.f, xm);                     // score + 1000 (>0)
            unsigned int t = (__float_as_uint(v) & 0xFFFFFF80u) | (unsigned int)p;
            #pragma unroll
            for (int j = 0; j < 8; ++j) {
                unsigned int mx = keys[r][j] > t ? keys[r][j] : t;
                unsigned int mn = keys[r][j] > t ? t : keys[r][j];
                keys[r][j] = mx; t = mn;
            }
        }
    }

    // dump keys: mK[row][lrow*8 + j], row = wave*16 + quad*4 + r
    const int mrow = wave * 16 + quad * 4;
    #pragma unroll
    for (int r = 0; r < 4; ++r) {
        uint4 k0 = make_uint4(keys[r][0], keys[r][1], keys[r][2], keys[r][3]);
        uint4 k1 = make_uint4(keys[r][4], keys[r][5], keys[r][6], keys[r][7]);
        *(uint4*)&mK[(mrow + r) * 128 + lrow * 8]     = k0;
        *(uint4*)&mK[(mrow + r) * 128 + lrow * 8 + 4] = k1;
    }
    __syncthreads();

    if (tid < 64) {
        unsigned int bk[NCH]; int bc[NCH];
        #pragma unroll
        for (int j = 0; j < NCH; ++j) { bk[j] = 0u; bc[j] = 0; }
        const unsigned int* rowK = mK + tid * 128;
        for (int c = 0; c < 128; ++c) {
            int pos = (tid + c) & 127;
            unsigned int k = rowK[pos];
            if (k > bk[NCH - 1]) {
                int lr = pos >> 3;
                int p  = (int)(k & 0x7Fu);
                int col = (half << 11) + (p << 4) + lr;
                bk[NCH - 1] = k; bc[NCH - 1] = col;
                #pragma unroll
                for (int j = NCH - 1; j > 0; --j) {
                    if (bk[j] > bk[j - 1]) {
                        unsigned int tk = bk[j]; bk[j] = bk[j - 1]; bk[j - 1] = tk;
                        int tc = bc[j]; bc[j] = bc[j - 1]; bc[j - 1] = tc;
                    }
                }
            }
        }
        int* co = cand + ((size_t)((b << 12) + n0 + tid)) * NCT + half * NCH;
        #pragma unroll
        for (int j = 0; j < NCH; ++j) co[j] = bc[j];
    }
}

// ---------------- Kernel 3: exact fp64 re-rank (parallel ranking) + gather/max -> feat ----------------
__global__ __launch_bounds__(256) void rerank_kernel(const float* __restrict__ x,
                                                     const double* __restrict__ xxd,
                                                     const int* __restrict__ cand,
                                                     float* __restrict__ feat) {
    __shared__ double sc[4][NCT];
    __shared__ int    si[4][NCT];
    __shared__ int    sel[4][KNN];
    const int tid = threadIdx.x, wave = tid >> 6, lane = tid & 63;
    const size_t row = (size_t)blockIdx.x * 4 + wave;     // 0..32767
    const int b = (int)(row >> 12);
    const float* xb = x + (((size_t)b) << 12) * CIN;
    const float* xn = x + row * CIN;

    const int cidx = lane & 31, part = lane >> 5;
    if (cidx < NCT) {
        int m = cand[row * NCT + cidx];
        const float* xm = xb + (size_t)m * CIN;
        const float* xa = xn + part * 32;
        const float* xv = xm + part * 32;
        double d = 0.0;
        #pragma unroll
        for (int c4 = 0; c4 < 8; ++c4) {
            float4 a = *(const float4*)&xa[c4 * 4];
            float4 v = *(const float4*)&xv[c4 * 4];
            d = fma((double)a.x, (double)v.x, d);
            d = fma((double)a.y, (double)v.y, d);
            d = fma((double)a.z, (double)v.z, d);
            d = fma((double)a.w, (double)v.w, d);
        }
        d += __shfl_xor(d, 32);
        if (part == 0) {
            sc[wave][cidx] = 2.0 * d - xxd[(((size_t)b) << 12) + m];
            si[wave][cidx] = m;
        }
    }
    __syncthreads();

    // parallel exact ranking: lane i counts candidates strictly ahead of it
    if (lane < NCT) {
        double myv = sc[wave][lane];
        int    mym = si[wave][lane];
        int rank = 0;
        #pragma unroll
        for (int c = 0; c < NCT; ++c) {
            double v = sc[wave][c];
            int    m = si[wave][c];
            rank += (v > myv || (v == myv && m < mym)) ? 1 : 0;
        }
        if (rank < KNN) sel[wave][rank] = mym;
    }
    __syncthreads();

    float mx = -3.0e38f;
    #pragma unroll
    for (int j = 0; j < KNN; ++j)
        mx = fmaxf(mx, xb[(size_t)sel[wave][j] * CIN + lane]);
    feat[row * CIN + lane] = mx;
}

// ---------------- Kernel 4: conv (fp32 VALU) -> y + BN stats ----------------
__global__ __launch_bounds__(256) void conv_stats_kernel(const float* __restrict__ feat,
                                                         const float* __restrict__ W,
                                                         float* __restrict__ y,
                                                         float* __restrict__ st) {
    __shared__ float Wt[64 * 128];   // Wt[c][o]
    __shared__ float Fs[64 * 64];
    __shared__ float bs[128], bs2[128];
    const int tid = threadIdx.x;
    const int n0  = blockIdx.x * 64;

    for (int i = tid; i < 8192; i += 256) {
        int o = i >> 6, c = i & 63;
        Wt[c * 128 + o] = W[i];
    }
    for (int i = tid; i < 1024; i += 256)
        ((float4*)Fs)[i] = ((const float4*)(feat + (size_t)n0 * CIN))[i];
    if (tid < 128) { bs[tid] = 0.f; bs2[tid] = 0.f; }
    __syncthreads();

    const int og = tid & 31, rg = tid >> 5;
    float ts[4] = {0.f, 0.f, 0.f, 0.f}, ts2[4] = {0.f, 0.f, 0.f, 0.f};
    #pragma unroll
    for (int p = 0; p < 4; ++p) {
        const int r0 = p * 16 + rg * 2;
        float acc0[4] = {0.f, 0.f, 0.f, 0.f}, acc1[4] = {0.f, 0.f, 0.f, 0.f};
        for (int c = 0; c < 64; ++c) {
            float f0 = Fs[r0 * 64 + c], f1 = Fs[(r0 + 1) * 64 + c];
            #pragma unroll
            for (int j = 0; j < 4; ++j) {
                float w = Wt[c * 128 + og + 32 * j];
                acc0[j] += f0 * w; acc1[j] += f1 * w;
            }
        }
        #pragma unroll
        for (int j = 0; j < 4; ++j) {
            const int ch = og + 32 * j;
            y[(size_t)(n0 + r0)     * COUT + ch] = acc0[j];
            y[(size_t)(n0 + r0 + 1) * COUT + ch] = acc1[j];
            ts[j]  += acc0[j] + acc1[j];
            ts2[j] += acc0[j] * acc0[j] + acc1[j] * acc1[j];
        }
    }
    #pragma unroll
    for (int j = 0; j < 4; ++j) {
        atomicAdd(&bs [og + 32 * j], ts[j]);
        atomicAdd(&bs2[og + 32 * j], ts2[j]);
    }
    __syncthreads();
    if (tid < 128) {
        atomicAdd(&st[tid],       bs[tid]);
        atomicAdd(&st[128 + tid], bs2[tid]);
    }
}

// ---------------- Kernel 5: elementwise BN + LeakyReLU -> fp32 out ----------------
__global__ __launch_bounds__(256) void norm_out_kernel(const float* __restrict__ y,
                                                       const float* __restrict__ st,
                                                       const float* __restrict__ gamma,
                                                       const float* __restrict__ beta,
                                                       float* __restrict__ out) {
    size_t i = ((size_t)blockIdx.x * 256 + threadIdx.x) * 4;
    int c0 = (int)(i & 127);
    float4 v = *(const float4*)&y[i];
    float o[4];
    const float inv = 1.0f / (float)TOTROWS;
    #pragma unroll
    for (int j = 0; j < 4; ++j) {
        int c = c0 + j;
        float m  = st[c] * inv;
        float vr = st[128 + c] * inv - m * m;
        float sc = rsqrtf(vr + 1e-5f) * gamma[c];
        float t  = (((const float*)&v)[j] - m) * sc + beta[c];
        o[j] = (t >= 0.f) ? t : 0.01f * t;
    }
    *(float4*)&out[i] = make_float4(o[0], o[1], o[2], o[3]);
}

extern "C" void kernel_launch(void* const* d_in, const int* in_sizes, int n_in,
                              void* d_out, int out_size, void* d_ws, size_t ws_size,
                              hipStream_t stream) {
    (void)in_sizes; (void)n_in; (void)out_size; (void)ws_size;
    const float* x     = (const float*)d_in[0];
    const float* W     = (const float*)d_in[1];
    const float* gamma = (const float*)d_in[2];
    const float* beta  = (const float*)d_in[3];
    // d_in[4] is k == 8 (compile-time KNN)
    float* out = (float*)d_out;

    // workspace (~28.4 MB): xxn 128K | xxd 256K | cand 4M | feat 8M | region 16M (xpack 4M, reused as y) | st
    char*   ws    = (char*)d_ws;
    float*  xxn   = (float*)ws;
    double* xxd   = (double*)(ws + 131072);
    int*    cand  = (int*)(ws + 131072 + 262144);
    float*  feat  = (float*)(ws + 131072 + 262144 + 4194304);
    unsigned short* xpack = (unsigned short*)(ws + 131072 + 262144 + 4194304 + 8388608);
    float*  y     = (float*)xpack;   // xpack (4 MB used) dead after knn_cand; y is 16 MB fp32
    float*  st    = (float*)(ws + 131072 + 262144 + 4194304 + 8388608 + 16777216);

    hipMemsetAsync(st, 0, 256 * sizeof(float), stream);
    prep_kernel      <<<TOTROWS * 8 / 256, 256, 0, stream>>>(x, xpack, xxn, xxd);
    knn_cand_kernel  <<<dim3(NPTS / 64, 2, BATCH), 256, 0, stream>>>(xpack, xxn, cand);
    rerank_kernel    <<<TOTROWS / 4, 256, 0, stream>>>(x, xxd, cand, feat);
    conv_stats_kernel<<<TOTROWS / 64, 256, 0, stream>>>(feat, W, y, st);
    norm_out_kernel  <<<(TOTROWS * COUT) / (256 * 4), 256, 0, stream>>>(y, st, gamma, beta, out);
}

// Round 12
// 347.004 us; speedup vs baseline: 1.3235x; 1.0408x over previous
//
#include <hip/hip_runtime.h>
#include <hip/hip_bf16.h>

#define NPTS 4096
#define CIN 64
#define COUT 128
#define BATCH 8
#define KNN 8
#define NCH 12              // candidates per column-half
#define NCT 24              // total candidates per row
#define TOTROWS (BATCH * NPTS)   // 32768

using short8 = __attribute__((ext_vector_type(8))) short;
using f32x4  = __attribute__((ext_vector_type(4))) float;

__device__ __forceinline__ unsigned short f2bf_rne(float f) {
    unsigned int u = __float_as_uint(f);
    unsigned int r = (u + 0x7fffu + ((u >> 16) & 1u)) >> 16;
    return (unsigned short)r;
}

// ---------------- Kernel 1: pack x -> bf16(RNE) rows (128B) + norms (xxn = 1000-xx fp32, xxd fp64) ----------------
__global__ __launch_bounds__(256) void prep_kernel(const float* __restrict__ x,
                                                   unsigned short* __restrict__ xpack,
                                                   float* __restrict__ xxn,
                                                   double* __restrict__ xxd) {
    int i   = blockIdx.x * 256 + threadIdx.x;    // 0 .. 262143
    int row = i >> 3, g = i & 7;                 // 8 threads per row
    const float* src = x + (size_t)row * CIN + g * 8;
    float4 v0 = *(const float4*)src;
    float4 v1 = *(const float4*)(src + 4);
    float f[8] = {v0.x, v0.y, v0.z, v0.w, v1.x, v1.y, v1.z, v1.w};

    unsigned int h[8];
    double s = 0.0;
    #pragma unroll
    for (int j = 0; j < 8; ++j) {
        h[j] = (unsigned int)f2bf_rne(f[j]);
        s += (double)f[j] * (double)f[j];
    }
    uint4 hi;
    hi.x = h[0] | (h[1] << 16); hi.y = h[2] | (h[3] << 16);
    hi.z = h[4] | (h[5] << 16); hi.w = h[6] | (h[7] << 16);
    *(uint4*)&xpack[(size_t)row * 64 + g * 8] = hi;

    s += __shfl_xor(s, 1);
    s += __shfl_xor(s, 2);
    s += __shfl_xor(s, 4);
    if (g == 0) { xxn[row] = 1000.f - (float)s; xxd[row] = s; }
}

// ---------------- Kernel 2: bf16 MFMA scores, 256-row LDS tiles (16 barriers), u32 top-8/lane -> top-12/half ----------------
// key = bits(float(score+1000)) with low 7 mantissa bits = chunk position p (0..127).
// col = half*2048 + p*16 + lrow. Per-lane 8-deep sorted u32 lists (4 rows) -> block merge -> top-12/half.
// bf16 score err + 0.008 trunc << rank8->12 margin; rerank is exact fp64.
__global__ __launch_bounds__(256) void knn_cand_kernel(const unsigned short* __restrict__ xpack,
                                                       const float* __restrict__ xxn,
                                                       int* __restrict__ cand) {
    __shared__ __align__(16) unsigned char SMEM[36864 + 1024];
    unsigned short* Bs  = (unsigned short*)SMEM;          // 256 rows x 72 ushorts
    float*          xxs = (float*)(SMEM + 36864);         // 256 floats
    unsigned int*   mK  = (unsigned int*)SMEM;            // 64*128 u32 merge scratch (after loop)

    const int tid  = threadIdx.x;
    const int n0   = blockIdx.x * 64;
    const int half = blockIdx.y;
    const int b    = blockIdx.z;
    const int wave = tid >> 6;
    const int lane = tid & 63;
    const int lrow = lane & 15;
    const int quad = lane >> 4;
    const int colbase = half << 11;                       // first candidate row of this half

    const unsigned short* xp = xpack + ((size_t)b << 12) * 64;
    const float* xnn = xxn + (b << 12);

    // A fragments: direct global load (L2-resident, coalesced)
    const int arow = n0 + wave * 16 + lrow;
    short8 ah0 = *(const short8*)&xp[arow * 64 + quad * 8];
    short8 ah1 = *(const short8*)&xp[arow * 64 + 32 + quad * 8];

    unsigned int keys[4][8];
    #pragma unroll
    for (int r = 0; r < 4; ++r)
        #pragma unroll
        for (int j = 0; j < 8; ++j) keys[r][j] = 0u;

    // preload tile 0 (256 candidate rows) into registers
    uint4 pr[8]; float pxv;
    {
        const size_t base = (size_t)colbase * 64;
        #pragma unroll
        for (int k = 0; k < 8; ++k) {
            int G = k * 256 + tid;                        // chunk 0..2047, coalesced per k
            pr[k] = *(const uint4*)&xp[base + G * 8];
        }
        pxv = xnn[colbase + tid];
    }

    for (int ot = 0; ot < 8; ++ot) {
        __syncthreads();                                  // prior tile's compute done
        #pragma unroll
        for (int k = 0; k < 8; ++k) {
            int G = k * 256 + tid, row = G >> 3, g = G & 7;
            *(uint4*)&Bs[row * 72 + g * 8] = pr[k];
        }
        xxs[tid] = pxv;
        __syncthreads();

        // issue prefetch for tile ot+1; whole compute phase covers the latency
        if (ot + 1 < 8) {
            const int rb2 = colbase + (ot + 1) * 256;
            const size_t base = (size_t)rb2 * 64;
            #pragma unroll
            for (int k = 0; k < 8; ++k) {
                int G = k * 256 + tid;
                pr[k] = *(const uint4*)&xp[base + G * 8];
            }
            pxv = xnn[rb2 + tid];
        }

        #pragma unroll 4
        for (int p2 = 0; p2 < 16; ++p2) {
            const int row0 = p2 * 16 + lrow;
            short8 bh0 = *(const short8*)&Bs[row0 * 72 + quad * 8];
            short8 bh1 = *(const short8*)&Bs[row0 * 72 + 32 + quad * 8];
            const float xm = xxs[row0];
            f32x4 acc = {0.f, 0.f, 0.f, 0.f};
            acc = __builtin_amdgcn_mfma_f32_16x16x32_bf16(ah0, bh0, acc, 0, 0, 0);
            acc = __builtin_amdgcn_mfma_f32_16x16x32_bf16(ah1, bh1, acc, 0, 0, 0);
            const unsigned int p = (unsigned int)(ot * 16 + p2);
            #pragma unroll
            for (int r = 0; r < 4; ++r) {
                float v = fmaf(acc[r], 2.f, xm);                     // score + 1000 (>0)
                unsigned int t = (__float_as_uint(v) & 0xFFFFFF80u) | p;
                #pragma unroll
                for (int j = 0; j < 8; ++j) {
                    unsigned int mx = keys[r][j] > t ? keys[r][j] : t;
                    unsigned int mn = keys[r][j] > t ? t : keys[r][j];
                    keys[r][j] = mx; t = mn;
                }
            }
        }
    }

    __syncthreads();                                      // all Bs reads done; reuse as mK
    const int mrow = wave * 16 + quad * 4;
    #pragma unroll
    for (int r = 0; r < 4; ++r) {
        uint4 k0 = make_uint4(keys[r][0], keys[r][1], keys[r][2], keys[r][3]);
        uint4 k1 = make_uint4(keys[r][4], keys[r][5], keys[r][6], keys[r][7]);
        *(uint4*)&mK[(mrow + r) * 128 + lrow * 8]     = k0;
        *(uint4*)&mK[(mrow + r) * 128 + lrow * 8 + 4] = k1;
    }
    __syncthreads();

    if (tid < 64) {
        unsigned int bk[NCH]; int bc[NCH];
        #pragma unroll
        for (int j = 0; j < NCH; ++j) { bk[j] = 0u; bc[j] = 0; }
        const unsigned int* rowK = mK + tid * 128;
        for (int c = 0; c < 128; ++c) {
            int pos = (tid + c) & 127;
            unsigned int k = rowK[pos];
            if (k > bk[NCH - 1]) {
                int lr = pos >> 3;
                int p  = (int)(k & 0x7Fu);
                int col = (half << 11) + (p << 4) + lr;
                bk[NCH - 1] = k; bc[NCH - 1] = col;
                #pragma unroll
                for (int j = NCH - 1; j > 0; --j) {
                    if (bk[j] > bk[j - 1]) {
                        unsigned int tk = bk[j]; bk[j] = bk[j - 1]; bk[j - 1] = tk;
                        int tc = bc[j]; bc[j] = bc[j - 1]; bc[j - 1] = tc;
                    }
                }
            }
        }
        int* co = cand + ((size_t)((b << 12) + n0 + tid)) * NCT + half * NCH;
        #pragma unroll
        for (int j = 0; j < NCH; ++j) co[j] = bc[j];
    }
}

// ---------------- Kernel 3: exact fp64 re-rank (parallel ranking) + gather/max -> feat ----------------
__global__ __launch_bounds__(256) void rerank_kernel(const float* __restrict__ x,
                                                     const double* __restrict__ xxd,
                                                     const int* __restrict__ cand,
                                                     float* __restrict__ feat) {
    __shared__ double sc[4][NCT];
    __shared__ int    si[4][NCT];
    __shared__ int    sel[4][KNN];
    const int tid = threadIdx.x, wave = tid >> 6, lane = tid & 63;
    const size_t row = (size_t)blockIdx.x * 4 + wave;     // 0..32767
    const int b = (int)(row >> 12);
    const float* xb = x + (((size_t)b) << 12) * CIN;
    const float* xn = x + row * CIN;

    const int cidx = lane & 31, part = lane >> 5;
    if (cidx < NCT) {
        int m = cand[row * NCT + cidx];
        const float* xm = xb + (size_t)m * CIN;
        const float* xa = xn + part * 32;
        const float* xv = xm + part * 32;
        double d = 0.0;
        #pragma unroll
        for (int c4 = 0; c4 < 8; ++c4) {
            float4 a = *(const float4*)&xa[c4 * 4];
            float4 v = *(const float4*)&xv[c4 * 4];
            d = fma((double)a.x, (double)v.x, d);
            d = fma((double)a.y, (double)v.y, d);
            d = fma((double)a.z, (double)v.z, d);
            d = fma((double)a.w, (double)v.w, d);
        }
        d += __shfl_xor(d, 32);
        if (part == 0) {
            sc[wave][cidx] = 2.0 * d - xxd[(((size_t)b) << 12) + m];
            si[wave][cidx] = m;
        }
    }
    __syncthreads();

    // parallel exact ranking: lane i counts candidates strictly ahead of it
    if (lane < NCT) {
        double myv = sc[wave][lane];
        int    mym = si[wave][lane];
        int rank = 0;
        #pragma unroll
        for (int c = 0; c < NCT; ++c) {
            double v = sc[wave][c];
            int    m = si[wave][c];
            rank += (v > myv || (v == myv && m < mym)) ? 1 : 0;
        }
        if (rank < KNN) sel[wave][rank] = mym;
    }
    __syncthreads();

    float mx = -3.0e38f;
    #pragma unroll
    for (int j = 0; j < KNN; ++j)
        mx = fmaxf(mx, xb[(size_t)sel[wave][j] * CIN + lane]);
    feat[row * CIN + lane] = mx;
}

// ---------------- Kernel 4: conv (fp32 VALU) -> y + BN stats ----------------
__global__ __launch_bounds__(256) void conv_stats_kernel(const float* __restrict__ feat,
                                                         const float* __restrict__ W,
                                                         float* __restrict__ y,
                                                         float* __restrict__ st) {
    __shared__ float Wt[64 * 128];   // Wt[c][o]
    __shared__ float Fs[64 * 64];
    __shared__ float bs[128], bs2[128];
    const int tid = threadIdx.x;
    const int n0  = blockIdx.x * 64;

    for (int i = tid; i < 8192; i += 256) {
        int o = i >> 6, c = i & 63;
        Wt[c * 128 + o] = W[i];
    }
    for (int i = tid; i < 1024; i += 256)
        ((float4*)Fs)[i] = ((const float4*)(feat + (size_t)n0 * CIN))[i];
    if (tid < 128) { bs[tid] = 0.f; bs2[tid] = 0.f; }
    __syncthreads();

    const int og = tid & 31, rg = tid >> 5;
    float ts[4] = {0.f, 0.f, 0.f, 0.f}, ts2[4] = {0.f, 0.f, 0.f, 0.f};
    #pragma unroll
    for (int p = 0; p < 4; ++p) {
        const int r0 = p * 16 + rg * 2;
        float acc0[4] = {0.f, 0.f, 0.f, 0.f}, acc1[4] = {0.f, 0.f, 0.f, 0.f};
        for (int c = 0; c < 64; ++c) {
            float f0 = Fs[r0 * 64 + c], f1 = Fs[(r0 + 1) * 64 + c];
            #pragma unroll
            for (int j = 0; j < 4; ++j) {
                float w = Wt[c * 128 + og + 32 * j];
                acc0[j] += f0 * w; acc1[j] += f1 * w;
            }
        }
        #pragma unroll
        for (int j = 0; j < 4; ++j) {
            const int ch = og + 32 * j;
            y[(size_t)(n0 + r0)     * COUT + ch] = acc0[j];
            y[(size_t)(n0 + r0 + 1) * COUT + ch] = acc1[j];
            ts[j]  += acc0[j] + acc1[j];
            ts2[j] += acc0[j] * acc0[j] + acc1[j] * acc1[j];
        }
    }
    #pragma unroll
    for (int j = 0; j < 4; ++j) {
        atomicAdd(&bs [og + 32 * j], ts[j]);
        atomicAdd(&bs2[og + 32 * j], ts2[j]);
    }
    __syncthreads();
    if (tid < 128) {
        atomicAdd(&st[tid],       bs[tid]);
        atomicAdd(&st[128 + tid], bs2[tid]);
    }
}

// ---------------- Kernel 5: elementwise BN + LeakyReLU -> fp32 out ----------------
__global__ __launch_bounds__(256) void norm_out_kernel(const float* __restrict__ y,
                                                       const float* __restrict__ st,
                                                       const float* __restrict__ gamma,
                                                       const float* __restrict__ beta,
                                                       float* __restrict__ out) {
    size_t i = ((size_t)blockIdx.x * 256 + threadIdx.x) * 4;
    int c0 = (int)(i & 127);
    float4 v = *(const float4*)&y[i];
    float o[4];
    const float inv = 1.0f / (float)TOTROWS;
    #pragma unroll
    for (int j = 0; j < 4; ++j) {
        int c = c0 + j;
        float m  = st[c] * inv;
        float vr = st[128 + c] * inv - m * m;
        float sc = rsqrtf(vr + 1e-5f) * gamma[c];
        float t  = (((const float*)&v)[j] - m) * sc + beta[c];
        o[j] = (t >= 0.f) ? t : 0.01f * t;
    }
    *(float4*)&out[i] = make_float4(o[0], o[1], o[2], o[3]);
}

extern "C" void kernel_launch(void* const* d_in, const int* in_sizes, int n_in,
                              void* d_out, int out_size, void* d_ws, size_t ws_size,
                              hipStream_t stream) {
    (void)in_sizes; (void)n_in; (void)out_size; (void)ws_size;
    const float* x     = (const float*)d_in[0];
    const float* W     = (const float*)d_in[1];
    const float* gamma = (const float*)d_in[2];
    const float* beta  = (const float*)d_in[3];
    // d_in[4] is k == 8 (compile-time KNN)
    float* out = (float*)d_out;

    // workspace (~28.4 MB): xxn 128K | xxd 256K | cand 4M | feat 8M | region 16M (xpack 4M, reused as y) | st
    char*   ws    = (char*)d_ws;
    float*  xxn   = (float*)ws;
    double* xxd   = (double*)(ws + 131072);
    int*    cand  = (int*)(ws + 131072 + 262144);
    float*  feat  = (float*)(ws + 131072 + 262144 + 4194304);
    unsigned short* xpack = (unsigned short*)(ws + 131072 + 262144 + 4194304 + 8388608);
    float*  y     = (float*)xpack;   // xpack (4 MB used) dead after knn_cand; y is 16 MB fp32
    float*  st    = (float*)(ws + 131072 + 262144 + 4194304 + 8388608 + 16777216);

    hipMemsetAsync(st, 0, 256 * sizeof(float), stream);
    prep_kernel      <<<TOTROWS * 8 / 256, 256, 0, stream>>>(x, xpack, xxn, xxd);
    knn_cand_kernel  <<<dim3(NPTS / 64, 2, BATCH), 256, 0, stream>>>(xpack, xxn, cand);
    rerank_kernel    <<<TOTROWS / 4, 256, 0, stream>>>(x, xxd, cand, feat);
    conv_stats_kernel<<<TOTROWS / 64, 256, 0, stream>>>(feat, W, y, st);
    norm_out_kernel  <<<(TOTROWS * COUT) / (256 * 4), 256, 0, stream>>>(y, st, gamma, beta, out);
}

// Round 13
// 339.404 us; speedup vs baseline: 1.3531x; 1.0224x over previous
//
#include <hip/hip_runtime.h>
#include <hip/hip_bf16.h>

#define NPTS 4096
#define CIN 64
#define COUT 128
#define BATCH 8
#define KNN 8
#define NCH 12              // candidates per column-half
#define NCT 24              // total candidates per row
#define TOTROWS (BATCH * NPTS)   // 32768

using short8 = __attribute__((ext_vector_type(8))) short;
using f32x4  = __attribute__((ext_vector_type(4))) float;

__device__ __forceinline__ unsigned short f2bf_rne(float f) {
    unsigned int u = __float_as_uint(f);
    unsigned int r = (u + 0x7fffu + ((u >> 16) & 1u)) >> 16;
    return (unsigned short)r;
}

// ---------------- Kernel 1: pack x -> bf16(RNE) rows (128B) + norms (xxn = 1000-xx fp32, xxd fp64) ----------------
__global__ __launch_bounds__(256) void prep_kernel(const float* __restrict__ x,
                                                   unsigned short* __restrict__ xpack,
                                                   float* __restrict__ xxn,
                                                   double* __restrict__ xxd) {
    int i   = blockIdx.x * 256 + threadIdx.x;    // 0 .. 262143
    int row = i >> 3, g = i & 7;                 // 8 threads per row
    const float* src = x + (size_t)row * CIN + g * 8;
    float4 v0 = *(const float4*)src;
    float4 v1 = *(const float4*)(src + 4);
    float f[8] = {v0.x, v0.y, v0.z, v0.w, v1.x, v1.y, v1.z, v1.w};

    unsigned int h[8];
    double s = 0.0;
    #pragma unroll
    for (int j = 0; j < 8; ++j) {
        h[j] = (unsigned int)f2bf_rne(f[j]);
        s += (double)f[j] * (double)f[j];
    }
    uint4 hi;
    hi.x = h[0] | (h[1] << 16); hi.y = h[2] | (h[3] << 16);
    hi.z = h[4] | (h[5] << 16); hi.w = h[6] | (h[7] << 16);
    *(uint4*)&xpack[(size_t)row * 64 + g * 8] = hi;

    s += __shfl_xor(s, 1);
    s += __shfl_xor(s, 2);
    s += __shfl_xor(s, 4);
    if (g == 0) { xxn[row] = 1000.f - (float)s; xxd[row] = s; }
}

// ---------------- Kernel 2: bf16 MFMA scores, 128-row double-buffered LDS tiles (1 barrier/tile) ----------------
// key = bits(float(score+1000)) with low 7 mantissa bits = chunk position p (0..127).
// col = half*2048 + p*16 + lrow. Per-lane 8-deep sorted u32 lists (4 rows) -> block merge -> top-12/half.
// bf16 score err + 0.008 trunc << rank8->12 margin; rerank is exact fp64.
__global__ __launch_bounds__(256, 3) void knn_cand_kernel(const unsigned short* __restrict__ xpack,
                                                          const float* __restrict__ xxn,
                                                          int* __restrict__ cand) {
    __shared__ __align__(16) unsigned char SMEM[45056];
    unsigned short* BUF0 = (unsigned short*)SMEM;            // 128 rows x 72 ushorts = 18432 B
    unsigned short* BUF1 = (unsigned short*)(SMEM + 18432);  // second buffer
    float*          xxs  = (float*)(SMEM + 36864);           // 2048 floats (norms for whole half)
    unsigned int*   mK   = (unsigned int*)SMEM;              // 32 KB merge scratch (overlays buffers)

    const int tid  = threadIdx.x;
    const int n0   = blockIdx.x * 64;
    const int half = blockIdx.y;
    const int b    = blockIdx.z;
    const int wave = tid >> 6;
    const int lane = tid & 63;
    const int lrow = lane & 15;
    const int quad = lane >> 4;
    const int colbase = half << 11;                          // first candidate row of this half

    const unsigned short* xp = xpack + ((size_t)b << 12) * 64;
    const float* xnn = xxn + (b << 12);

    // A fragments: direct global load (L2-resident, coalesced)
    const int arow = n0 + wave * 16 + lrow;
    short8 ah0 = *(const short8*)&xp[arow * 64 + quad * 8];
    short8 ah1 = *(const short8*)&xp[arow * 64 + 32 + quad * 8];

    // stage norms for the whole half once (2048 floats)
    #pragma unroll
    for (int k = 0; k < 2; ++k) {
        int i = k * 256 + tid;                               // 0..511 float4s
        float4 v = *(const float4*)&xnn[colbase + i * 4];
        *(float4*)&xxs[i * 4] = v;
    }

    unsigned int keys[4][8];
    #pragma unroll
    for (int r = 0; r < 4; ++r)
        #pragma unroll
        for (int j = 0; j < 8; ++j) keys[r][j] = 0u;

    // priming: tile0 -> BUF0, tile1 -> pr
    uint4 pr[4];
    {
        const size_t base0 = (size_t)colbase * 64;
        #pragma unroll
        for (int k = 0; k < 4; ++k) {
            int G = k * 256 + tid;                           // chunk 0..1023
            pr[k] = *(const uint4*)&xp[base0 + G * 8];
        }
        #pragma unroll
        for (int k = 0; k < 4; ++k) {
            int G = k * 256 + tid, row = G >> 3, g = G & 7;
            *(uint4*)&BUF0[row * 72 + g * 8] = pr[k];
        }
        const size_t base1 = (size_t)(colbase + 128) * 64;
        #pragma unroll
        for (int k = 0; k < 4; ++k) {
            int G = k * 256 + tid;
            pr[k] = *(const uint4*)&xp[base1 + G * 8];
        }
    }
    __syncthreads();

    for (int ot = 0; ot < 16; ++ot) {
        unsigned short* cur = (ot & 1) ? BUF1 : BUF0;
        unsigned short* nxt = (ot & 1) ? BUF0 : BUF1;

        // a) write pr (tile ot+1) into nxt — concurrent with compute reads on cur
        if (ot < 15) {
            #pragma unroll
            for (int k = 0; k < 4; ++k) {
                int G = k * 256 + tid, row = G >> 3, g = G & 7;
                *(uint4*)&nxt[row * 72 + g * 8] = pr[k];
            }
        }
        // b) issue loads for tile ot+2
        if (ot < 14) {
            const size_t base = (size_t)(colbase + (ot + 2) * 128) * 64;
            #pragma unroll
            for (int k = 0; k < 4; ++k) {
                int G = k * 256 + tid;
                pr[k] = *(const uint4*)&xp[base + G * 8];
            }
        }

        // c) compute on cur (tile ot)
        const int xbase = ot * 128;
        #pragma unroll 4
        for (int p2 = 0; p2 < 8; ++p2) {
            const int row0 = p2 * 16 + lrow;
            short8 bh0 = *(const short8*)&cur[row0 * 72 + quad * 8];
            short8 bh1 = *(const short8*)&cur[row0 * 72 + 32 + quad * 8];
            const float xm = xxs[xbase + row0];
            f32x4 acc = {0.f, 0.f, 0.f, 0.f};
            acc = __builtin_amdgcn_mfma_f32_16x16x32_bf16(ah0, bh0, acc, 0, 0, 0);
            acc = __builtin_amdgcn_mfma_f32_16x16x32_bf16(ah1, bh1, acc, 0, 0, 0);
            const unsigned int p = (unsigned int)(ot * 8 + p2);
            #pragma unroll
            for (int r = 0; r < 4; ++r) {
                float v = fmaf(acc[r], 2.f, xm);                     // score + 1000 (>0)
                unsigned int t = (__float_as_uint(v) & 0xFFFFFF80u) | p;
                #pragma unroll
                for (int j = 0; j < 8; ++j) {
                    unsigned int mx = keys[r][j] > t ? keys[r][j] : t;
                    unsigned int mn = keys[r][j] > t ? t : keys[r][j];
                    keys[r][j] = mx; t = mn;
                }
            }
        }
        // d) one barrier per tile
        __syncthreads();
    }

    // dump keys: mK[row][lrow*8 + j], row = wave*16 + quad*4 + r
    const int mrow = wave * 16 + quad * 4;
    #pragma unroll
    for (int r = 0; r < 4; ++r) {
        uint4 k0 = make_uint4(keys[r][0], keys[r][1], keys[r][2], keys[r][3]);
        uint4 k1 = make_uint4(keys[r][4], keys[r][5], keys[r][6], keys[r][7]);
        *(uint4*)&mK[(mrow + r) * 128 + lrow * 8]     = k0;
        *(uint4*)&mK[(mrow + r) * 128 + lrow * 8 + 4] = k1;
    }
    __syncthreads();

    if (tid < 64) {
        unsigned int bk[NCH]; int bc[NCH];
        #pragma unroll
        for (int j = 0; j < NCH; ++j) { bk[j] = 0u; bc[j] = 0; }
        const unsigned int* rowK = mK + tid * 128;
        for (int c = 0; c < 128; ++c) {
            int pos = (tid + c) & 127;
            unsigned int k = rowK[pos];
            if (k > bk[NCH - 1]) {
                int lr = pos >> 3;
                int p  = (int)(k & 0x7Fu);
                int col = (half << 11) + (p << 4) + lr;
                bk[NCH - 1] = k; bc[NCH - 1] = col;
                #pragma unroll
                for (int j = NCH - 1; j > 0; --j) {
                    if (bk[j] > bk[j - 1]) {
                        unsigned int tk = bk[j]; bk[j] = bk[j - 1]; bk[j - 1] = tk;
                        int tc = bc[j]; bc[j] = bc[j - 1]; bc[j - 1] = tc;
                    }
                }
            }
        }
        int* co = cand + ((size_t)((b << 12) + n0 + tid)) * NCT + half * NCH;
        #pragma unroll
        for (int j = 0; j < NCH; ++j) co[j] = bc[j];
    }
}

// ---------------- Kernel 3: exact fp64 re-rank (parallel ranking) + gather/max -> feat ----------------
__global__ __launch_bounds__(256) void rerank_kernel(const float* __restrict__ x,
                                                     const double* __restrict__ xxd,
                                                     const int* __restrict__ cand,
                                                     float* __restrict__ feat) {
    __shared__ double sc[4][NCT];
    __shared__ int    si[4][NCT];
    __shared__ int    sel[4][KNN];
    const int tid = threadIdx.x, wave = tid >> 6, lane = tid & 63;
    const size_t row = (size_t)blockIdx.x * 4 + wave;     // 0..32767
    const int b = (int)(row >> 12);
    const float* xb = x + (((size_t)b) << 12) * CIN;
    const float* xn = x + row * CIN;

    const int cidx = lane & 31, part = lane >> 5;
    if (cidx < NCT) {
        int m = cand[row * NCT + cidx];
        const float* xm = xb + (size_t)m * CIN;
        const float* xa = xn + part * 32;
        const float* xv = xm + part * 32;
        double d = 0.0;
        #pragma unroll
        for (int c4 = 0; c4 < 8; ++c4) {
            float4 a = *(const float4*)&xa[c4 * 4];
            float4 v = *(const float4*)&xv[c4 * 4];
            d = fma((double)a.x, (double)v.x, d);
            d = fma((double)a.y, (double)v.y, d);
            d = fma((double)a.z, (double)v.z, d);
            d = fma((double)a.w, (double)v.w, d);
        }
        d += __shfl_xor(d, 32);
        if (part == 0) {
            sc[wave][cidx] = 2.0 * d - xxd[(((size_t)b) << 12) + m];
            si[wave][cidx] = m;
        }
    }
    __syncthreads();

    // parallel exact ranking: lane i counts candidates strictly ahead of it
    if (lane < NCT) {
        double myv = sc[wave][lane];
        int    mym = si[wave][lane];
        int rank = 0;
        #pragma unroll
        for (int c = 0; c < NCT; ++c) {
            double v = sc[wave][c];
            int    m = si[wave][c];
            rank += (v > myv || (v == myv && m < mym)) ? 1 : 0;
        }
        if (rank < KNN) sel[wave][rank] = mym;
    }
    __syncthreads();

    float mx = -3.0e38f;
    #pragma unroll
    for (int j = 0; j < KNN; ++j)
        mx = fmaxf(mx, xb[(size_t)sel[wave][j] * CIN + lane]);
    feat[row * CIN + lane] = mx;
}

// ---------------- Kernel 4: conv (fp32 VALU) -> y + BN stats ----------------
__global__ __launch_bounds__(256) void conv_stats_kernel(const float* __restrict__ feat,
                                                         const float* __restrict__ W,
                                                         float* __restrict__ y,
                                                         float* __restrict__ st) {
    __shared__ float Wt[64 * 128];   // Wt[c][o]
    __shared__ float Fs[64 * 64];
    __shared__ float bs[128], bs2[128];
    const int tid = threadIdx.x;
    const int n0  = blockIdx.x * 64;

    for (int i = tid; i < 8192; i += 256) {
        int o = i >> 6, c = i & 63;
        Wt[c * 128 + o] = W[i];
    }
    for (int i = tid; i < 1024; i += 256)
        ((float4*)Fs)[i] = ((const float4*)(feat + (size_t)n0 * CIN))[i];
    if (tid < 128) { bs[tid] = 0.f; bs2[tid] = 0.f; }
    __syncthreads();

    const int og = tid & 31, rg = tid >> 5;
    float ts[4] = {0.f, 0.f, 0.f, 0.f}, ts2[4] = {0.f, 0.f, 0.f, 0.f};
    #pragma unroll
    for (int p = 0; p < 4; ++p) {
        const int r0 = p * 16 + rg * 2;
        float acc0[4] = {0.f, 0.f, 0.f, 0.f}, acc1[4] = {0.f, 0.f, 0.f, 0.f};
        for (int c = 0; c < 64; ++c) {
            float f0 = Fs[r0 * 64 + c], f1 = Fs[(r0 + 1) * 64 + c];
            #pragma unroll
            for (int j = 0; j < 4; ++j) {
                float w = Wt[c * 128 + og + 32 * j];
                acc0[j] += f0 * w; acc1[j] += f1 * w;
            }
        }
        #pragma unroll
        for (int j = 0; j < 4; ++j) {
            const int ch = og + 32 * j;
            y[(size_t)(n0 + r0)     * COUT + ch] = acc0[j];
            y[(size_t)(n0 + r0 + 1) * COUT + ch] = acc1[j];
            ts[j]  += acc0[j] + acc1[j];
            ts2[j] += acc0[j] * acc0[j] + acc1[j] * acc1[j];
        }
    }
    #pragma unroll
    for (int j = 0; j < 4; ++j) {
        atomicAdd(&bs [og + 32 * j], ts[j]);
        atomicAdd(&bs2[og + 32 * j], ts2[j]);
    }
    __syncthreads();
    if (tid < 128) {
        atomicAdd(&st[tid],       bs[tid]);
        atomicAdd(&st[128 + tid], bs2[tid]);
    }
}

// ---------------- Kernel 5: elementwise BN + LeakyReLU -> fp32 out ----------------
__global__ __launch_bounds__(256) void norm_out_kernel(const float* __restrict__ y,
                                                       const float* __restrict__ st,
                                                       const float* __restrict__ gamma,
                                                       const float* __restrict__ beta,
                                                       float* __restrict__ out) {
    size_t i = ((size_t)blockIdx.x * 256 + threadIdx.x) * 4;
    int c0 = (int)(i & 127);
    float4 v = *(const float4*)&y[i];
    float o[4];
    const float inv = 1.0f / (float)TOTROWS;
    #pragma unroll
    for (int j = 0; j < 4; ++j) {
        int c = c0 + j;
        float m  = st[c] * inv;
        float vr = st[128 + c] * inv - m * m;
        float sc = rsqrtf(vr + 1e-5f) * gamma[c];
        float t  = (((const float*)&v)[j] - m) * sc + beta[c];
        o[j] = (t >= 0.f) ? t : 0.01f * t;
    }
    *(float4*)&out[i] = make_float4(o[0], o[1], o[2], o[3]);
}

extern "C" void kernel_launch(void* const* d_in, const int* in_sizes, int n_in,
                              void* d_out, int out_size, void* d_ws, size_t ws_size,
                              hipStream_t stream) {
    (void)in_sizes; (void)n_in; (void)out_size; (void)ws_size;
    const float* x     = (const float*)d_in[0];
    const float* W     = (const float*)d_in[1];
    const float* gamma = (const float*)d_in[2];
    const float* beta  = (const float*)d_in[3];
    // d_in[4] is k == 8 (compile-time KNN)
    float* out = (float*)d_out;

    // workspace (~28.4 MB): xxn 128K | xxd 256K | cand 4M | feat 8M | region 16M (xpack 4M, reused as y) | st
    char*   ws    = (char*)d_ws;
    float*  xxn   = (float*)ws;
    double* xxd   = (double*)(ws + 131072);
    int*    cand  = (int*)(ws + 131072 + 262144);
    float*  feat  = (float*)(ws + 131072 + 262144 + 4194304);
    unsigned short* xpack = (unsigned short*)(ws + 131072 + 262144 + 4194304 + 8388608);
    float*  y     = (float*)xpack;   // xpack (4 MB used) dead after knn_cand; y is 16 MB fp32
    float*  st    = (float*)(ws + 131072 + 262144 + 4194304 + 8388608 + 16777216);

    hipMemsetAsync(st, 0, 256 * sizeof(float), stream);
    prep_kernel      <<<TOTROWS * 8 / 256, 256, 0, stream>>>(x, xpack, xxn, xxd);
    knn_cand_kernel  <<<dim3(NPTS / 64, 2, BATCH), 256, 0, stream>>>(xpack, xxn, cand);
    rerank_kernel    <<<TOTROWS / 4, 256, 0, stream>>>(x, xxd, cand, feat);
    conv_stats_kernel<<<TOTROWS / 64, 256, 0, stream>>>(feat, W, y, st);
    norm_out_kernel  <<<(TOTROWS * COUT) / (256 * 4), 256, 0, stream>>>(y, st, gamma, beta, out);
}

// Round 14
// 332.526 us; speedup vs baseline: 1.3811x; 1.0207x over previous
//
#include <hip/hip_runtime.h>
#include <hip/hip_bf16.h>

#define NPTS 4096
#define CIN 64
#define COUT 128
#define BATCH 8
#define KNN 8
#define NCH 12              // candidates per column-half
#define NCT 24              // total candidates per row
#define TOTROWS (BATCH * NPTS)   // 32768

using short8 = __attribute__((ext_vector_type(8))) short;
using f32x4  = __attribute__((ext_vector_type(4))) float;

__device__ __forceinline__ unsigned short f2bf_rne(float f) {
    unsigned int u = __float_as_uint(f);
    unsigned int r = (u + 0x7fffu + ((u >> 16) & 1u)) >> 16;
    return (unsigned short)r;
}

// ---------------- Kernel 1: pack x -> bf16(RNE) rows (128B) + norms (xxn = 1000-xx fp32, xxd fp64) ----------------
__global__ __launch_bounds__(256) void prep_kernel(const float* __restrict__ x,
                                                   unsigned short* __restrict__ xpack,
                                                   float* __restrict__ xxn,
                                                   double* __restrict__ xxd) {
    int i   = blockIdx.x * 256 + threadIdx.x;    // 0 .. 262143
    int row = i >> 3, g = i & 7;                 // 8 threads per row
    const float* src = x + (size_t)row * CIN + g * 8;
    float4 v0 = *(const float4*)src;
    float4 v1 = *(const float4*)(src + 4);
    float f[8] = {v0.x, v0.y, v0.z, v0.w, v1.x, v1.y, v1.z, v1.w};

    unsigned int h[8];
    double s = 0.0;
    #pragma unroll
    for (int j = 0; j < 8; ++j) {
        h[j] = (unsigned int)f2bf_rne(f[j]);
        s += (double)f[j] * (double)f[j];
    }
    uint4 hi;
    hi.x = h[0] | (h[1] << 16); hi.y = h[2] | (h[3] << 16);
    hi.z = h[4] | (h[5] << 16); hi.w = h[6] | (h[7] << 16);
    *(uint4*)&xpack[(size_t)row * 64 + g * 8] = hi;

    s += __shfl_xor(s, 1);
    s += __shfl_xor(s, 2);
    s += __shfl_xor(s, 4);
    if (g == 0) { xxn[row] = 1000.f - (float)s; xxd[row] = s; }
}

// ---------------- Kernel 2: bf16 MFMA scores, 128-row dbuf LDS tiles, 1 barrier/tile, no cross-barrier regs ----------------
// key = bits(float(score+1000)) with low 7 mantissa bits = chunk position p (0..127).
// col = half*2048 + p*16 + lrow. Per-lane 8-deep sorted u32 lists (4 rows) -> block merge -> top-12/half.
// bf16 score err + 0.008 trunc << rank8->12 margin; rerank is exact fp64.
__global__ __launch_bounds__(256) void knn_cand_kernel(const unsigned short* __restrict__ xpack,
                                                       const float* __restrict__ xxn,
                                                       int* __restrict__ cand) {
    __shared__ __align__(16) unsigned char SMEM[37888];
    unsigned short* BUF0 = (unsigned short*)SMEM;            // 128 rows x 72 ushorts = 18432 B
    unsigned short* BUF1 = (unsigned short*)(SMEM + 18432);  // second buffer
    float*          xxs  = (float*)(SMEM + 36864);           // 2 x 128 norms (double-buffered)
    unsigned int*   mK   = (unsigned int*)SMEM;              // 32 KB merge scratch (overlays buffers)

    const int tid  = threadIdx.x;
    const int n0   = blockIdx.x * 64;
    const int half = blockIdx.y;
    const int b    = blockIdx.z;
    const int wave = tid >> 6;
    const int lane = tid & 63;
    const int lrow = lane & 15;
    const int quad = lane >> 4;
    const int colbase = half << 11;                          // first candidate row of this half

    const unsigned short* xp = xpack + ((size_t)b << 12) * 64;
    const float* xnn = xxn + (b << 12);

    // A fragments: direct global load (L2-resident, coalesced)
    const int arow = n0 + wave * 16 + lrow;
    short8 ah0 = *(const short8*)&xp[arow * 64 + quad * 8];
    short8 ah1 = *(const short8*)&xp[arow * 64 + 32 + quad * 8];

    unsigned int keys[4][8];
    #pragma unroll
    for (int r = 0; r < 4; ++r)
        #pragma unroll
        for (int j = 0; j < 8; ++j) keys[r][j] = 0u;

    uint4 pr[4]; float pxv;

    // priming: tile 0 -> BUF0 + xxs[0]; pr dead before first barrier
    {
        const size_t base0 = (size_t)colbase * 64;
        #pragma unroll
        for (int k = 0; k < 4; ++k) {
            int G = k * 256 + tid;                           // chunk 0..1023
            pr[k] = *(const uint4*)&xp[base0 + G * 8];
        }
        pxv = (tid < 128) ? xnn[colbase + tid] : 0.f;
        #pragma unroll
        for (int k = 0; k < 4; ++k) {
            int G = k * 256 + tid, row = G >> 3, g = G & 7;
            *(uint4*)&BUF0[row * 72 + g * 8] = pr[k];
        }
        if (tid < 128) xxs[tid] = pxv;
    }
    __syncthreads();

    for (int ot = 0; ot < 16; ++ot) {
        unsigned short* cur = (ot & 1) ? BUF1 : BUF0;
        unsigned short* nxt = (ot & 1) ? BUF0 : BUF1;
        const float*    xs  = xxs + (ot & 1) * 128;

        // a) issue loads for tile ot+1 (in flight during compute)
        if (ot < 15) {
            const size_t base = (size_t)(colbase + (ot + 1) * 128) * 64;
            #pragma unroll
            for (int k = 0; k < 4; ++k) {
                int G = k * 256 + tid;
                pr[k] = *(const uint4*)&xp[base + G * 8];
            }
            if (tid < 128) pxv = xnn[colbase + (ot + 1) * 128 + tid];
        }

        // b) compute on cur (tile ot)
        #pragma unroll 4
        for (int p2 = 0; p2 < 8; ++p2) {
            const int row0 = p2 * 16 + lrow;
            short8 bh0 = *(const short8*)&cur[row0 * 72 + quad * 8];
            short8 bh1 = *(const short8*)&cur[row0 * 72 + 32 + quad * 8];
            const float xm = xs[row0];
            f32x4 acc = {0.f, 0.f, 0.f, 0.f};
            acc = __builtin_amdgcn_mfma_f32_16x16x32_bf16(ah0, bh0, acc, 0, 0, 0);
            acc = __builtin_amdgcn_mfma_f32_16x16x32_bf16(ah1, bh1, acc, 0, 0, 0);
            const unsigned int p = (unsigned int)(ot * 8 + p2);
            #pragma unroll
            for (int r = 0; r < 4; ++r) {
                float v = fmaf(acc[r], 2.f, xm);                     // score + 1000 (>0)
                unsigned int t = (__float_as_uint(v) & 0xFFFFFF80u) | p;
                #pragma unroll
                for (int j = 0; j < 8; ++j) {
                    unsigned int mx = keys[r][j] > t ? keys[r][j] : t;
                    unsigned int mn = keys[r][j] > t ? t : keys[r][j];
                    keys[r][j] = mx; t = mn;
                }
            }
        }

        // c) write prefetch into nxt BEFORE the barrier (pr not live across barrier -> no spill)
        if (ot < 15) {
            #pragma unroll
            for (int k = 0; k < 4; ++k) {
                int G = k * 256 + tid, row = G >> 3, g = G & 7;
                *(uint4*)&nxt[row * 72 + g * 8] = pr[k];
            }
            if (tid < 128) xxs[(1 - (ot & 1)) * 128 + tid] = pxv;
        }
        // d) single barrier per tile
        __syncthreads();
    }

    // dump keys: mK[row][lrow*8 + j], row = wave*16 + quad*4 + r
    const int mrow = wave * 16 + quad * 4;
    #pragma unroll
    for (int r = 0; r < 4; ++r) {
        uint4 k0 = make_uint4(keys[r][0], keys[r][1], keys[r][2], keys[r][3]);
        uint4 k1 = make_uint4(keys[r][4], keys[r][5], keys[r][6], keys[r][7]);
        *(uint4*)&mK[(mrow + r) * 128 + lrow * 8]     = k0;
        *(uint4*)&mK[(mrow + r) * 128 + lrow * 8 + 4] = k1;
    }
    __syncthreads();

    if (tid < 64) {
        unsigned int bk[NCH]; int bc[NCH];
        #pragma unroll
        for (int j = 0; j < NCH; ++j) { bk[j] = 0u; bc[j] = 0; }
        const unsigned int* rowK = mK + tid * 128;
        for (int c = 0; c < 128; ++c) {
            int pos = (tid + c) & 127;
            unsigned int k = rowK[pos];
            if (k > bk[NCH - 1]) {
                int lr = pos >> 3;
                int p  = (int)(k & 0x7Fu);
                int col = (half << 11) + (p << 4) + lr;
                bk[NCH - 1] = k; bc[NCH - 1] = col;
                #pragma unroll
                for (int j = NCH - 1; j > 0; --j) {
                    if (bk[j] > bk[j - 1]) {
                        unsigned int tk = bk[j]; bk[j] = bk[j - 1]; bk[j - 1] = tk;
                        int tc = bc[j]; bc[j] = bc[j - 1]; bc[j - 1] = tc;
                    }
                }
            }
        }
        int* co = cand + ((size_t)((b << 12) + n0 + tid)) * NCT + half * NCH;
        #pragma unroll
        for (int j = 0; j < NCH; ++j) co[j] = bc[j];
    }
}

// ---------------- Kernel 3: exact fp64 re-rank (parallel ranking) + gather/max -> feat ----------------
__global__ __launch_bounds__(256) void rerank_kernel(const float* __restrict__ x,
                                                     const double* __restrict__ xxd,
                                                     const int* __restrict__ cand,
                                                     float* __restrict__ feat) {
    __shared__ double sc[4][NCT];
    __shared__ int    si[4][NCT];
    __shared__ int    sel[4][KNN];
    const int tid = threadIdx.x, wave = tid >> 6, lane = tid & 63;
    const size_t row = (size_t)blockIdx.x * 4 + wave;     // 0..32767
    const int b = (int)(row >> 12);
    const float* xb = x + (((size_t)b) << 12) * CIN;
    const float* xn = x + row * CIN;

    const int cidx = lane & 31, part = lane >> 5;
    if (cidx < NCT) {
        int m = cand[row * NCT + cidx];
        const float* xm = xb + (size_t)m * CIN;
        const float* xa = xn + part * 32;
        const float* xv = xm + part * 32;
        double d = 0.0;
        #pragma unroll
        for (int c4 = 0; c4 < 8; ++c4) {
            float4 a = *(const float4*)&xa[c4 * 4];
            float4 v = *(const float4*)&xv[c4 * 4];
            d = fma((double)a.x, (double)v.x, d);
            d = fma((double)a.y, (double)v.y, d);
            d = fma((double)a.z, (double)v.z, d);
            d = fma((double)a.w, (double)v.w, d);
        }
        d += __shfl_xor(d, 32);
        if (part == 0) {
            sc[wave][cidx] = 2.0 * d - xxd[(((size_t)b) << 12) + m];
            si[wave][cidx] = m;
        }
    }
    __syncthreads();

    // parallel exact ranking: lane i counts candidates strictly ahead of it
    if (lane < NCT) {
        double myv = sc[wave][lane];
        int    mym = si[wave][lane];
        int rank = 0;
        #pragma unroll
        for (int c = 0; c < NCT; ++c) {
            double v = sc[wave][c];
            int    m = si[wave][c];
            rank += (v > myv || (v == myv && m < mym)) ? 1 : 0;
        }
        if (rank < KNN) sel[wave][rank] = mym;
    }
    __syncthreads();

    float mx = -3.0e38f;
    #pragma unroll
    for (int j = 0; j < KNN; ++j)
        mx = fmaxf(mx, xb[(size_t)sel[wave][j] * CIN + lane]);
    feat[row * CIN + lane] = mx;
}

// ---------------- Kernel 4: conv (fp32 VALU) -> y + BN stats ----------------
__global__ __launch_bounds__(256) void conv_stats_kernel(const float* __restrict__ feat,
                                                         const float* __restrict__ W,
                                                         float* __restrict__ y,
                                                         float* __restrict__ st) {
    __shared__ float Wt[64 * 128];   // Wt[c][o]
    __shared__ float Fs[64 * 64];
    __shared__ float bs[128], bs2[128];
    const int tid = threadIdx.x;
    const int n0  = blockIdx.x * 64;

    for (int i = tid; i < 8192; i += 256) {
        int o = i >> 6, c = i & 63;
        Wt[c * 128 + o] = W[i];
    }
    for (int i = tid; i < 1024; i += 256)
        ((float4*)Fs)[i] = ((const float4*)(feat + (size_t)n0 * CIN))[i];
    if (tid < 128) { bs[tid] = 0.f; bs2[tid] = 0.f; }
    __syncthreads();

    const int og = tid & 31, rg = tid >> 5;
    float ts[4] = {0.f, 0.f, 0.f, 0.f}, ts2[4] = {0.f, 0.f, 0.f, 0.f};
    #pragma unroll
    for (int p = 0; p < 4; ++p) {
        const int r0 = p * 16 + rg * 2;
        float acc0[4] = {0.f, 0.f, 0.f, 0.f}, acc1[4] = {0.f, 0.f, 0.f, 0.f};
        for (int c = 0; c < 64; ++c) {
            float f0 = Fs[r0 * 64 + c], f1 = Fs[(r0 + 1) * 64 + c];
            #pragma unroll
            for (int j = 0; j < 4; ++j) {
                float w = Wt[c * 128 + og + 32 * j];
                acc0[j] += f0 * w; acc1[j] += f1 * w;
            }
        }
        #pragma unroll
        for (int j = 0; j < 4; ++j) {
            const int ch = og + 32 * j;
            y[(size_t)(n0 + r0)     * COUT + ch] = acc0[j];
            y[(size_t)(n0 + r0 + 1) * COUT + ch] = acc1[j];
            ts[j]  += acc0[j] + acc1[j];
            ts2[j] += acc0[j] * acc0[j] + acc1[j] * acc1[j];
        }
    }
    #pragma unroll
    for (int j = 0; j < 4; ++j) {
        atomicAdd(&bs [og + 32 * j], ts[j]);
        atomicAdd(&bs2[og + 32 * j], ts2[j]);
    }
    __syncthreads();
    if (tid < 128) {
        atomicAdd(&st[tid],       bs[tid]);
        atomicAdd(&st[128 + tid], bs2[tid]);
    }
}

// ---------------- Kernel 5: elementwise BN + LeakyReLU -> fp32 out ----------------
__global__ __launch_bounds__(256) void norm_out_kernel(const float* __restrict__ y,
                                                       const float* __restrict__ st,
                                                       const float* __restrict__ gamma,
                                                       const float* __restrict__ beta,
                                                       float* __restrict__ out) {
    size_t i = ((size_t)blockIdx.x * 256 + threadIdx.x) * 4;
    int c0 = (int)(i & 127);
    float4 v = *(const float4*)&y[i];
    float o[4];
    const float inv = 1.0f / (float)TOTROWS;
    #pragma unroll
    for (int j = 0; j < 4; ++j) {
        int c = c0 + j;
        float m  = st[c] * inv;
        float vr = st[128 + c] * inv - m * m;
        float sc = rsqrtf(vr + 1e-5f) * gamma[c];
        float t  = (((const float*)&v)[j] - m) * sc + beta[c];
        o[j] = (t >= 0.f) ? t : 0.01f * t;
    }
    *(float4*)&out[i] = make_float4(o[0], o[1], o[2], o[3]);
}

extern "C" void kernel_launch(void* const* d_in, const int* in_sizes, int n_in,
                              void* d_out, int out_size, void* d_ws, size_t ws_size,
                              hipStream_t stream) {
    (void)in_sizes; (void)n_in; (void)out_size; (void)ws_size;
    const float* x     = (const float*)d_in[0];
    const float* W     = (const float*)d_in[1];
    const float* gamma = (const float*)d_in[2];
    const float* beta  = (const float*)d_in[3];
    // d_in[4] is k == 8 (compile-time KNN)
    float* out = (float*)d_out;

    // workspace (~28.4 MB): xxn 128K | xxd 256K | cand 4M | feat 8M | region 16M (xpack 4M, reused as y) | st
    char*   ws    = (char*)d_ws;
    float*  xxn   = (float*)ws;
    double* xxd   = (double*)(ws + 131072);
    int*    cand  = (int*)(ws + 131072 + 262144);
    float*  feat  = (float*)(ws + 131072 + 262144 + 4194304);
    unsigned short* xpack = (unsigned short*)(ws + 131072 + 262144 + 4194304 + 8388608);
    float*  y     = (float*)xpack;   // xpack (4 MB used) dead after knn_cand; y is 16 MB fp32
    float*  st    = (float*)(ws + 131072 + 262144 + 4194304 + 8388608 + 16777216);

    hipMemsetAsync(st, 0, 256 * sizeof(float), stream);
    prep_kernel      <<<TOTROWS * 8 / 256, 256, 0, stream>>>(x, xpack, xxn, xxd);
    knn_cand_kernel  <<<dim3(NPTS / 64, 2, BATCH), 256, 0, stream>>>(xpack, xxn, cand);
    rerank_kernel    <<<TOTROWS / 4, 256, 0, stream>>>(x, xxd, cand, feat);
    conv_stats_kernel<<<TOTROWS / 64, 256, 0, stream>>>(feat, W, y, st);
    norm_out_kernel  <<<(TOTROWS * COUT) / (256 * 4), 256, 0, stream>>>(y, st, gamma, beta, out);
}